// Round 2
// baseline (1250.489 us; speedup 1.0000x reference)
//
#include <hip/hip_runtime.h>
#include <hip/hip_bf16.h>

// ---------------------------------------------------------------------------
// 6-layer transformer forward, MI355X. f16 MFMA compute, f32 accum/residuals.
// Round 2: fix output dtype (reference returns float32 -> d_out is float*).
// ---------------------------------------------------------------------------

typedef _Float16 f16_t;
typedef _Float16 f16x8 __attribute__((ext_vector_type(8)));
typedef _Float16 f16x2 __attribute__((ext_vector_type(2)));
typedef float    f32x4 __attribute__((ext_vector_type(4)));

#define LSTR 3145728LL  // per-layer transposed-weight stride (f16 elems)

// ---------------- generic batched GEMM: C = A[M,K] * (Bt[N,K])^T + bias -----
// A, Bt f16 row-major. Batch z: zh=z/zmod, zl=z%zmod; offsets per operand.
template<int BM, int BN, int WR, int WC, int OUTF16, int RELU>
__global__ void __launch_bounds__(256)
gemm_kernel(const f16_t* __restrict__ A, const f16_t* __restrict__ B,
            const float* __restrict__ bias, void* __restrict__ Cout,
            int M, int N, int K, int lda, int ldb, int ldc, int zmod,
            long long sAhi, long long sAlo, long long sBhi, long long sBlo,
            long long sChi, long long sClo)
{
    constexpr int BK   = 32;
    constexpr int PADK = 40;            // 80B row stride: 16B-aligned, 2-way banks
    constexpr int WMT  = BM / WR;
    constexpr int WNT  = BN / WC;
    constexpr int MR   = WMT / 16;
    constexpr int NR   = WNT / 16;
    __shared__ __align__(16) f16_t As[BM][PADK];
    __shared__ __align__(16) f16_t Bs[BN][PADK];

    const int tid  = threadIdx.x;
    const int wid  = tid >> 6, lane = tid & 63;
    const int wr   = wid / WC, wc = wid % WC;
    const int z    = blockIdx.z;
    const int zh   = z / zmod, zl = z % zmod;
    const f16_t* Ab = A + (long long)zh * sAhi + (long long)zl * sAlo;
    const f16_t* Bb = B + (long long)zh * sBhi + (long long)zl * sBlo;
    const int m0 = blockIdx.x * BM;
    const int n0 = blockIdx.y * BN;

    f32x4 acc[MR][NR] = {};

    const int l15  = lane & 15;
    const int kc   = (lane >> 4) * 8;   // A/B frag: 8 contiguous k per lane
    const int srow = tid >> 2;
    const int sc8  = (tid & 3) * 8;

    for (int k0 = 0; k0 < K; k0 += BK) {
        __syncthreads();
        for (int rr = srow; rr < BM; rr += 64)
            *(f16x8*)&As[rr][sc8] = *(const f16x8*)&Ab[(long long)(m0 + rr) * lda + k0 + sc8];
        for (int rr = srow; rr < BN; rr += 64)
            *(f16x8*)&Bs[rr][sc8] = *(const f16x8*)&Bb[(long long)(n0 + rr) * ldb + k0 + sc8];
        __syncthreads();
        f16x8 af[MR], bf[NR];
#pragma unroll
        for (int m = 0; m < MR; ++m) af[m] = *(const f16x8*)&As[wr * WMT + m * 16 + l15][kc];
#pragma unroll
        for (int n = 0; n < NR; ++n) bf[n] = *(const f16x8*)&Bs[wc * WNT + n * 16 + l15][kc];
#pragma unroll
        for (int m = 0; m < MR; ++m)
#pragma unroll
            for (int n = 0; n < NR; ++n)
                acc[m][n] = __builtin_amdgcn_mfma_f32_16x16x32_f16(af[m], bf[n], acc[m][n], 0, 0, 0);
    }

    const long long cOff = (long long)zh * sChi + (long long)zl * sClo;
    const int rbase = (lane >> 4) * 4;  // C/D: row=(lane>>4)*4+r, col=lane&15 (m89)
#pragma unroll
    for (int m = 0; m < MR; ++m) {
        const int row = m0 + wr * WMT + m * 16 + rbase;
#pragma unroll
        for (int n = 0; n < NR; ++n) {
            const int col = n0 + wc * WNT + n * 16 + l15;
            const float bb = bias ? bias[col] : 0.0f;
#pragma unroll
            for (int r = 0; r < 4; ++r) {
                float v = acc[m][n][r] + bb;
                if (RELU) v = fmaxf(v, 0.0f);
                const long long idx = cOff + (long long)(row + r) * ldc + col;
                if (OUTF16) ((f16_t*)Cout)[idx] = (f16_t)v;
                else        ((float*)Cout)[idx] = v;
            }
        }
    }
}

// ---------------- weight convert+transpose f32 -> f16, [K,N] -> [N,K] -------
__global__ void wconv_kernel(const float* __restrict__ Wq, const float* __restrict__ Wk,
                             const float* __restrict__ Wv, const float* __restrict__ Wo,
                             const float* __restrict__ W1, const float* __restrict__ W2,
                             f16_t* __restrict__ wT)
{
    __shared__ float tile[32][33];
    const int t     = blockIdx.x;       // 18432 tiles = 6 layers * 3072
    const int layer = t / 3072;
    const int r     = t % 3072;
    const float* src; f16_t* dst; int R, C, tt;
    if (r < 1024) {                     // Wq,Wk,Wv,Wo: [512,512]
        const int mat = r >> 8; tt = r & 255; R = 512; C = 512;
        const float* s4 = (mat == 0) ? Wq : (mat == 1) ? Wk : (mat == 2) ? Wv : Wo;
        src = s4 + (long long)layer * 262144;
        dst = wT + (long long)layer * LSTR + (long long)mat * 262144;
    } else if (r < 2048) {              // W1: [512,2048] -> [2048,512]
        tt = r - 1024; R = 512; C = 2048;
        src = W1 + (long long)layer * 1048576;
        dst = wT + (long long)layer * LSTR + 1048576;
    } else {                            // W2: [2048,512] -> [512,2048]
        tt = r - 2048; R = 2048; C = 512;
        src = W2 + (long long)layer * 1048576;
        dst = wT + (long long)layer * LSTR + 2097152;
    }
    const int tC = C >> 5;
    const int tr = tt / tC, tc = tt % tC;
    const int r0 = tr * 32, c0 = tc * 32;
    const int tx = threadIdx.x, ty = threadIdx.y;
#pragma unroll
    for (int i = 0; i < 4; ++i)
        tile[ty + 8 * i][tx] = src[(long long)(r0 + ty + 8 * i) * C + c0 + tx];
    __syncthreads();
#pragma unroll
    for (int i = 0; i < 4; ++i)
        dst[(long long)(c0 + ty + 8 * i) * R + r0 + tx] = (f16_t)tile[tx][ty + 8 * i];
}

// ---------------- concat per-layer [bq|bk|bv] -> [6][1536] ------------------
__global__ void biascat_kernel(const float* __restrict__ bq, const float* __restrict__ bk,
                               const float* __restrict__ bv, float* __restrict__ qkvb)
{
    const int i = blockIdx.x * 256 + threadIdx.x;
    if (i >= 9216) return;
    const int l = i / 1536, c = i % 1536;
    float v;
    if (c < 512)       v = bq[l * 512 + c];
    else if (c < 1024) v = bk[l * 512 + c - 512];
    else               v = bv[l * 512 + c - 1024];
    qkvb[i] = v;
}

// ---------------- embedding gather + sinusoidal PE --------------------------
__global__ void embed_kernel(const int* __restrict__ xt, const float* __restrict__ emb,
                             float* __restrict__ h32, f16_t* __restrict__ hb)
{
    const int row = blockIdx.x;         // b*512 + t
    const int t   = row & 511;
    const int tok = xt[row];
    const int tid = threadIdx.x;
#pragma unroll
    for (int s = 0; s < 2; ++s) {
        const int d = tid + s * 256;
        const int i = d >> 1;
        const float inv = expf((float)(2 * i) * (-9.210340371976184f / 512.0f));
        const float ang = (float)t * inv;
        const float pe  = (d & 1) ? cosf(ang) : sinf(ang);
        const float v   = emb[(long long)tok * 512 + d] + pe;
        h32[(long long)row * 512 + d] = v;
        hb [(long long)row * 512 + d] = (f16_t)v;
    }
}

// ---------------- row softmax over 512, in place (f16) ----------------------
__global__ void softmax_kernel(f16_t* __restrict__ S)
{
    __shared__ float red[4];
    const long long row = blockIdx.x;
    f16_t* p = S + row * 512;
    const int tid = threadIdx.x;
    f16x2 v = *(f16x2*)&p[2 * tid];
    float v0 = (float)v[0], v1 = (float)v[1];
    float m = fmaxf(v0, v1);
#pragma unroll
    for (int o = 32; o > 0; o >>= 1) m = fmaxf(m, __shfl_down(m, o, 64));
    if ((tid & 63) == 0) red[tid >> 6] = m;
    __syncthreads();
    m = fmaxf(fmaxf(red[0], red[1]), fmaxf(red[2], red[3]));
    const float e0 = __expf(v0 - m), e1 = __expf(v1 - m);
    float s = e0 + e1;
#pragma unroll
    for (int o = 32; o > 0; o >>= 1) s += __shfl_down(s, o, 64);
    __syncthreads();
    if ((tid & 63) == 0) red[tid >> 6] = s;
    __syncthreads();
    s = red[0] + red[1] + red[2] + red[3];
    const float inv = 1.0f / s;
    f16x2 o2; o2[0] = (f16_t)(e0 * inv); o2[1] = (f16_t)(e1 * inv);
    *(f16x2*)&p[2 * tid] = o2;
}

// ---------------- h = LN(X + h); also write f16 copy ------------------------
__global__ void add_ln_kernel(const float* __restrict__ X, float* __restrict__ H,
                              const float* __restrict__ g, const float* __restrict__ b,
                              f16_t* __restrict__ Hf)
{
    __shared__ float red[4], red2[4];
    const long long row = blockIdx.x;
    const float* x = X + row * 512;
    float* h = H + row * 512;
    const int tid = threadIdx.x;
    const float s0 = x[tid] + h[tid];
    const float s1 = x[tid + 256] + h[tid + 256];
    float sum = s0 + s1, sq = s0 * s0 + s1 * s1;
#pragma unroll
    for (int o = 32; o > 0; o >>= 1) { sum += __shfl_down(sum, o, 64); sq += __shfl_down(sq, o, 64); }
    if ((tid & 63) == 0) { red[tid >> 6] = sum; red2[tid >> 6] = sq; }
    __syncthreads();
    sum = red[0] + red[1] + red[2] + red[3];
    sq  = red2[0] + red2[1] + red2[2] + red2[3];
    const float mu = sum * (1.0f / 512.0f);
    float var = sq * (1.0f / 512.0f) - mu * mu;
    var = fmaxf(var, 0.0f);
    const float rs = rsqrtf(var + 1e-5f);
    const float o0 = g[tid] * (s0 - mu) * rs + b[tid];
    const float o1 = g[tid + 256] * (s1 - mu) * rs + b[tid + 256];
    h[tid] = o0; h[tid + 256] = o1;
    Hf[row * 512 + tid]       = (f16_t)o0;
    Hf[row * 512 + tid + 256] = (f16_t)o1;
}

// ---------------- V_head [T,64] -> Vt [64,T] per (b,h) ----------------------
__global__ void vtrans_kernel(const f16_t* __restrict__ qkv, f16_t* __restrict__ Vt)
{
    __shared__ f16_t tl[32][34];
    const int z  = blockIdx.y;          // b*8 + h
    const int b  = z >> 3, hh = z & 7;
    const int tile = blockIdx.x;        // 0..31: 16 t-tiles x 2 c-tiles
    const int tr = tile >> 1, tc = tile & 1;
    const int t0 = tr * 32, c0 = tc * 32;
    const int tx = threadIdx.x, ty = threadIdx.y;
#pragma unroll
    for (int i = 0; i < 4; ++i)
        tl[ty + 8 * i][tx] = qkv[(long long)(b * 512 + t0 + ty + 8 * i) * 1536 + 1024 + hh * 64 + c0 + tx];
    __syncthreads();
#pragma unroll
    for (int i = 0; i < 4; ++i)
        Vt[((long long)z * 64 + c0 + ty + 8 * i) * 512 + t0 + tx] = tl[tx][ty + 8 * i];
}

// ---------------- classifier head: split reduction --------------------------
__global__ void head_partial_kernel(const float* __restrict__ h32, const float* __restrict__ Wout,
                                    float* __restrict__ partials)
{
    const int blk = blockIdx.x;         // 8 b * 64 chunks
    const int b = blk >> 6, chunk = blk & 63;
    const int tid = threadIdx.x;
    const float* hp = h32 + (long long)b * 262144 + (long long)chunk * 4096;
    float a0 = 0, a1 = 0, a2 = 0, a3 = 0, a4 = 0;
    for (int it = 0; it < 16; ++it) {
        const int idx = it * 256 + tid;
        const float hv = hp[idx];
        const float* w = Wout + ((long long)chunk * 4096 + idx) * 5;
        a0 += hv * w[0]; a1 += hv * w[1]; a2 += hv * w[2]; a3 += hv * w[3]; a4 += hv * w[4];
    }
#pragma unroll
    for (int o = 32; o > 0; o >>= 1) {
        a0 += __shfl_down(a0, o, 64); a1 += __shfl_down(a1, o, 64); a2 += __shfl_down(a2, o, 64);
        a3 += __shfl_down(a3, o, 64); a4 += __shfl_down(a4, o, 64);
    }
    __shared__ float sm[4][5];
    const int lane = tid & 63, w = tid >> 6;
    if (lane == 0) { sm[w][0] = a0; sm[w][1] = a1; sm[w][2] = a2; sm[w][3] = a3; sm[w][4] = a4; }
    __syncthreads();
    if (tid < 5)
        partials[(long long)blk * 5 + tid] = sm[0][tid] + sm[1][tid] + sm[2][tid] + sm[3][tid];
}

__global__ void head_final_kernel(const float* __restrict__ partials, const float* __restrict__ bout,
                                  float* __restrict__ out)
{
    const int tid = threadIdx.x;
    if (tid >= 40) return;
    const int b = tid / 5, c = tid % 5;
    float s = bout[c];
    const float* p = partials + (long long)b * 64 * 5 + c;
    for (int ck = 0; ck < 64; ++ck) s += p[ck * 5];
    out[tid] = s;   // reference output dtype is float32 -> d_out is float*
}

// ---------------------------------------------------------------------------
extern "C" void kernel_launch(void* const* d_in, const int* in_sizes, int n_in,
                              void* d_out, int out_size, void* d_ws, size_t ws_size,
                              hipStream_t stream)
{
    (void)in_sizes; (void)n_in; (void)out_size; (void)ws_size;
    const int*   x_tok = (const int*)  d_in[0];
    const float* emb   = (const float*)d_in[2];
    const float* Wq    = (const float*)d_in[3];
    const float* bq    = (const float*)d_in[4];
    const float* Wk    = (const float*)d_in[5];
    const float* bk    = (const float*)d_in[6];
    const float* Wv    = (const float*)d_in[7];
    const float* bv    = (const float*)d_in[8];
    const float* Wo    = (const float*)d_in[9];
    const float* bo    = (const float*)d_in[10];
    const float* gma   = (const float*)d_in[11];
    const float* bta   = (const float*)d_in[12];
    const float* W1    = (const float*)d_in[13];
    const float* b1    = (const float*)d_in[14];
    const float* W2    = (const float*)d_in[15];
    const float* b2    = (const float*)d_in[16];
    const float* Wout  = (const float*)d_in[17];
    const float* bout  = (const float*)d_in[18];

    char* ws = (char*)d_ws;
    size_t off = 0;
    auto take = [&](size_t bytes) { char* p = ws + off; off += (bytes + 255) & ~(size_t)255; return p; };
    f16_t* wT    = (f16_t*)take(18874368ULL * 2);  // transposed f16 weights
    f16_t* hb    = (f16_t*)take(2097152ULL * 2);   // h, f16 copy
    f16_t* qkv   = (f16_t*)take(6291456ULL * 2);   // [4096][1536]
    f16_t* S     = (f16_t*)take(16777216ULL * 2);  // [64][512][512] scores/probs
    f16_t* Vt    = (f16_t*)take(2097152ULL * 2);   // [64][64][512]
    f16_t* ao    = (f16_t*)take(2097152ULL * 2);   // attn out [4096][512]
    f16_t* f1    = (f16_t*)take(8388608ULL * 2);   // ffn hidden [4096][2048]
    float* qkvb  = (float*)take(9216ULL * 4);
    float* h32   = (float*)take(2097152ULL * 4);   // residual stream f32
    float* t32   = (float*)take(2097152ULL * 4);   // pre-LN branch f32
    float* parts = (float*)take(2560ULL * 4);

    wconv_kernel <<<dim3(18432), dim3(32, 8), 0, stream>>>(Wq, Wk, Wv, Wo, W1, W2, wT);
    biascat_kernel<<<dim3(36), 256, 0, stream>>>(bq, bk, bv, qkvb);
    embed_kernel <<<dim3(4096), 256, 0, stream>>>(x_tok, emb, h32, hb);

    for (int l = 0; l < 6; ++l) {
        const f16_t* wl = wT + (long long)l * LSTR;
        // QKV: [4096,512] @ [512,1536] -> qkv f16
        gemm_kernel<128,128,2,2,1,0><<<dim3(32,12,1),256,0,stream>>>(hb, wl, qkvb + l*1536, qkv,
            4096,1536,512, 512,512,1536, 1, 0,0,0,0,0,0);
        vtrans_kernel<<<dim3(32,64), dim3(32,8), 0, stream>>>(qkv, Vt);
        // scores: per (b,h): Q[512,64] @ K^T -> S f16
        gemm_kernel<128,128,2,2,1,0><<<dim3(4,4,64),256,0,stream>>>(qkv, qkv + 512, nullptr, S,
            512,512,64, 1536,1536,512, 8, 786432LL,64LL, 786432LL,64LL, 2097152LL,262144LL);
        softmax_kernel<<<dim3(32768),256,0,stream>>>(S);
        // PV: P[512,512] @ Vt^T[512,64] -> ao (cols h*64..)
        gemm_kernel<128,64,4,1,1,0><<<dim3(4,1,64),256,0,stream>>>(S, Vt, nullptr, ao,
            512,64,512, 512,512,512, 8, 2097152LL,262144LL, 262144LL,32768LL, 262144LL,64LL);
        // O proj -> t32 f32
        gemm_kernel<128,64,4,1,0,0><<<dim3(32,8,1),256,0,stream>>>(ao, wl + 786432, bo + l*512, t32,
            4096,512,512, 512,512,512, 1, 0,0,0,0,0,0);
        add_ln_kernel<<<dim3(4096),256,0,stream>>>(t32, h32, gma + l*512, bta + l*512, hb);
        // FFN1 + relu -> f1 f16
        gemm_kernel<128,128,2,2,1,1><<<dim3(32,16,1),256,0,stream>>>(hb, wl + 1048576, b1 + l*2048, f1,
            4096,2048,512, 512,512,2048, 1, 0,0,0,0,0,0);
        // FFN2 -> t32 f32
        gemm_kernel<128,64,4,1,0,0><<<dim3(32,8,1),256,0,stream>>>(f1, wl + 2097152, b2 + l*512, t32,
            4096,512,2048, 2048,2048,512, 1, 0,0,0,0,0,0);
        add_ln_kernel<<<dim3(4096),256,0,stream>>>(t32, h32, gma + l*512, bta + l*512, hb);
    }

    head_partial_kernel<<<dim3(512),256,0,stream>>>(h32, Wout, parts);
    head_final_kernel  <<<dim3(1),64,0,stream>>>(parts, bout, (float*)d_out);
}

// Round 3
// 879.434 us; speedup vs baseline: 1.4219x; 1.4219x over previous
//
#include <hip/hip_runtime.h>
#include <hip/hip_bf16.h>

// ---------------------------------------------------------------------------
// 6-layer transformer forward, MI355X. f16 MFMA compute, f32 accum/residuals.
// Round 3: 2-phase pipelined GEMM (global_load_lds + dbuf LDS + swizzle),
//          split-K for N=512 GEMMs (reduce fused into add_ln), PV 64x64.
// ---------------------------------------------------------------------------

typedef _Float16 f16_t;
typedef _Float16 f16x8 __attribute__((ext_vector_type(8)));
typedef _Float16 f16x2 __attribute__((ext_vector_type(2)));
typedef float    f32x4 __attribute__((ext_vector_type(4)));

#define LSTR 3145728LL  // per-layer transposed-weight stride (f16 elems)

__device__ __forceinline__ void gl_lds16(const f16_t* g, f16_t* l) {
    __builtin_amdgcn_global_load_lds(
        (const __attribute__((address_space(1))) unsigned int*)g,
        (__attribute__((address_space(3))) unsigned int*)l, 16, 0, 0);
}

// ---------------- pipelined batched GEMM: C = A[M,K] * (Bt[N,K])^T + bias ---
// A, Bt f16 row-major. blockIdx.z -> zh=z/zmod, zl=z%zmod; per-operand strides.
// Split-K is expressed via zmod=1, sAhi/sBhi = K-slice offset, sChi = C-slice.
// LDS: linear dest (global_load_lds), XOR-swizzled k-chunk (rule #21: swizzle
// applied to BOTH global source and LDS read offset).
template<int BM, int BN, int WR, int WC, int OUTF16, int RELU>
__global__ void __launch_bounds__(256)
gemm_kernel(const f16_t* __restrict__ A, const f16_t* __restrict__ B,
            const float* __restrict__ bias, void* __restrict__ Cout,
            int M, int N, int K, int lda, int ldb, int ldc, int zmod,
            long long sAhi, long long sAlo, long long sBhi, long long sBlo,
            long long sChi, long long sClo)
{
    constexpr int BK  = 32;
    constexpr int WMT = BM / WR;
    constexpr int WNT = BN / WC;
    constexpr int MR  = WMT / 16;
    constexpr int NR  = WNT / 16;
    constexpr int IA  = BM / 64;        // global_load_lds issues per thread (A)
    constexpr int IB  = BN / 64;
    __shared__ __align__(16) f16_t As[2][BM][BK];
    __shared__ __align__(16) f16_t Bs[2][BN][BK];

    const int tid  = threadIdx.x;
    const int wid  = tid >> 6, lane = tid & 63;
    const int wr   = wid / WC, wc = wid % WC;
    const int z    = blockIdx.z;
    const int zh   = z / zmod, zl = z % zmod;
    const f16_t* Ab = A + (long long)zh * sAhi + (long long)zl * sAlo;
    const f16_t* Bb = B + (long long)zh * sBhi + (long long)zl * sBlo;
    const int m0 = blockIdx.x * BM;
    const int n0 = blockIdx.y * BN;

    f32x4 acc[MR][NR] = {};

    // ---- staging addresses: chunk c = i*256+tid; row=c>>2, kchunk=(c&3)^swz
    const f16_t* srcA[IA]; const f16_t* srcB[IB];
#pragma unroll
    for (int i = 0; i < IA; ++i) {
        const int c = i * 256 + tid, row = c >> 2;
        const int kch = (c & 3) ^ ((row >> 1) & 3);
        srcA[i] = Ab + (long long)(m0 + row) * lda + kch * 8;
    }
#pragma unroll
    for (int i = 0; i < IB; ++i) {
        const int c = i * 256 + tid, row = c >> 2;
        const int kch = (c & 3) ^ ((row >> 1) & 3);
        srcB[i] = Bb + (long long)(n0 + row) * ldb + kch * 8;
    }
    auto stage = [&](int bf_, int t) {
        const int k0 = t * BK;
#pragma unroll
        for (int i = 0; i < IA; ++i)
            gl_lds16(srcA[i] + k0, &As[bf_][0][0] + (i * 256 + wid * 64) * 8);
#pragma unroll
        for (int i = 0; i < IB; ++i)
            gl_lds16(srcB[i] + k0, &Bs[bf_][0][0] + (i * 256 + wid * 64) * 8);
    };

    // ---- fragment read offsets (bytes), swizzled to match staged layout
    const int l15 = lane & 15;
    const int kc  = (lane >> 4) * 8;    // 8 contiguous k per lane
    int aoff[MR], boff[NR];
#pragma unroll
    for (int m = 0; m < MR; ++m) {
        const int row = wr * WMT + m * 16 + l15;
        aoff[m] = ((row * BK + kc) * 2) ^ (((row >> 1) & 3) << 4);
    }
#pragma unroll
    for (int n = 0; n < NR; ++n) {
        const int row = wc * WNT + n * 16 + l15;
        boff[n] = ((row * BK + kc) * 2) ^ (((row >> 1) & 3) << 4);
    }

    const int NT = K / BK;
    stage(0, 0);
    __syncthreads();                    // drains vmcnt before barrier

    int buf = 0;
    for (int t = 0; t < NT; ++t) {
        if (t + 1 < NT) stage(buf ^ 1, t + 1);   // loads fly during MFMA
        const char* Al = (const char*)&As[buf][0][0];
        const char* Bl = (const char*)&Bs[buf][0][0];
        f16x8 af[MR], bfr[NR];
#pragma unroll
        for (int m = 0; m < MR; ++m) af[m]  = *(const f16x8*)(Al + aoff[m]);
#pragma unroll
        for (int n = 0; n < NR; ++n) bfr[n] = *(const f16x8*)(Bl + boff[n]);
#pragma unroll
        for (int m = 0; m < MR; ++m)
#pragma unroll
            for (int n = 0; n < NR; ++n)
                acc[m][n] = __builtin_amdgcn_mfma_f32_16x16x32_f16(af[m], bfr[n], acc[m][n], 0, 0, 0);
        __syncthreads();                // drains vmcnt+lgkmcnt, swap safe
        buf ^= 1;
    }

    const long long cOff = (long long)zh * sChi + (long long)zl * sClo;
    const int rbase = (lane >> 4) * 4;  // C/D: row=(lane>>4)*4+r, col=lane&15
#pragma unroll
    for (int m = 0; m < MR; ++m) {
        const int row = m0 + wr * WMT + m * 16 + rbase;
#pragma unroll
        for (int n = 0; n < NR; ++n) {
            const int col = n0 + wc * WNT + n * 16 + l15;
            const float bb = bias ? bias[col] : 0.0f;
#pragma unroll
            for (int r = 0; r < 4; ++r) {
                float v = acc[m][n][r] + bb;
                if (RELU) v = fmaxf(v, 0.0f);
                const long long idx = cOff + (long long)(row + r) * ldc + col;
                if (OUTF16) ((f16_t*)Cout)[idx] = (f16_t)v;
                else        ((float*)Cout)[idx] = v;
            }
        }
    }
}

// ---------------- weight convert+transpose f32 -> f16, [K,N] -> [N,K] -------
__global__ void wconv_kernel(const float* __restrict__ Wq, const float* __restrict__ Wk,
                             const float* __restrict__ Wv, const float* __restrict__ Wo,
                             const float* __restrict__ W1, const float* __restrict__ W2,
                             f16_t* __restrict__ wT)
{
    __shared__ float tile[32][33];
    const int t     = blockIdx.x;       // 18432 tiles = 6 layers * 3072
    const int layer = t / 3072;
    const int r     = t % 3072;
    const float* src; f16_t* dst; int R, C, tt;
    if (r < 1024) {                     // Wq,Wk,Wv,Wo: [512,512]
        const int mat = r >> 8; tt = r & 255; R = 512; C = 512;
        const float* s4 = (mat == 0) ? Wq : (mat == 1) ? Wk : (mat == 2) ? Wv : Wo;
        src = s4 + (long long)layer * 262144;
        dst = wT + (long long)layer * LSTR + (long long)mat * 262144;
    } else if (r < 2048) {              // W1: [512,2048] -> [2048,512]
        tt = r - 1024; R = 512; C = 2048;
        src = W1 + (long long)layer * 1048576;
        dst = wT + (long long)layer * LSTR + 1048576;
    } else {                            // W2: [2048,512] -> [512,2048]
        tt = r - 2048; R = 2048; C = 512;
        src = W2 + (long long)layer * 1048576;
        dst = wT + (long long)layer * LSTR + 2097152;
    }
    const int tC = C >> 5;
    const int tr = tt / tC, tc = tt % tC;
    const int r0 = tr * 32, c0 = tc * 32;
    const int tx = threadIdx.x, ty = threadIdx.y;
#pragma unroll
    for (int i = 0; i < 4; ++i)
        tile[ty + 8 * i][tx] = src[(long long)(r0 + ty + 8 * i) * C + c0 + tx];
    __syncthreads();
#pragma unroll
    for (int i = 0; i < 4; ++i)
        dst[(long long)(c0 + ty + 8 * i) * R + r0 + tx] = (f16_t)tile[tx][ty + 8 * i];
}

// ---------------- concat per-layer [bq|bk|bv] -> [6][1536] ------------------
__global__ void biascat_kernel(const float* __restrict__ bq, const float* __restrict__ bk,
                               const float* __restrict__ bv, float* __restrict__ qkvb)
{
    const int i = blockIdx.x * 256 + threadIdx.x;
    if (i >= 9216) return;
    const int l = i / 1536, c = i % 1536;
    float v;
    if (c < 512)       v = bq[l * 512 + c];
    else if (c < 1024) v = bk[l * 512 + c - 512];
    else               v = bv[l * 512 + c - 1024];
    qkvb[i] = v;
}

// ---------------- embedding gather + sinusoidal PE --------------------------
__global__ void embed_kernel(const int* __restrict__ xt, const float* __restrict__ emb,
                             float* __restrict__ h32, f16_t* __restrict__ hb)
{
    const int row = blockIdx.x;         // b*512 + t
    const int t   = row & 511;
    const int tok = xt[row];
    const int tid = threadIdx.x;
#pragma unroll
    for (int s = 0; s < 2; ++s) {
        const int d = tid + s * 256;
        const int i = d >> 1;
        const float inv = expf((float)(2 * i) * (-9.210340371976184f / 512.0f));
        const float ang = (float)t * inv;
        const float pe  = (d & 1) ? cosf(ang) : sinf(ang);
        const float v   = emb[(long long)tok * 512 + d] + pe;
        h32[(long long)row * 512 + d] = v;
        hb [(long long)row * 512 + d] = (f16_t)v;
    }
}

// ---------------- row softmax over 512, in place (f16) ----------------------
__global__ void softmax_kernel(f16_t* __restrict__ S)
{
    __shared__ float red[4];
    const long long row = blockIdx.x;
    f16_t* p = S + row * 512;
    const int tid = threadIdx.x;
    f16x2 v = *(f16x2*)&p[2 * tid];
    float v0 = (float)v[0], v1 = (float)v[1];
    float m = fmaxf(v0, v1);
#pragma unroll
    for (int o = 32; o > 0; o >>= 1) m = fmaxf(m, __shfl_down(m, o, 64));
    if ((tid & 63) == 0) red[tid >> 6] = m;
    __syncthreads();
    m = fmaxf(fmaxf(red[0], red[1]), fmaxf(red[2], red[3]));
    const float e0 = __expf(v0 - m), e1 = __expf(v1 - m);
    float s = e0 + e1;
#pragma unroll
    for (int o = 32; o > 0; o >>= 1) s += __shfl_down(s, o, 64);
    __syncthreads();
    if ((tid & 63) == 0) red[tid >> 6] = s;
    __syncthreads();
    s = red[0] + red[1] + red[2] + red[3];
    const float inv = 1.0f / s;
    f16x2 o2; o2[0] = (f16_t)(e0 * inv); o2[1] = (f16_t)(e1 * inv);
    *(f16x2*)&p[2 * tid] = o2;
}

// ------- h = LN( sum_{s<ns} X[s] + bias + h ); also write f16 copy ----------
__global__ void add_ln_kernel(const float* __restrict__ X, int ns, long long sstr,
                              const float* __restrict__ bias,
                              float* __restrict__ H,
                              const float* __restrict__ g, const float* __restrict__ b,
                              f16_t* __restrict__ Hf)
{
    __shared__ float red[4], red2[4];
    const long long row = blockIdx.x;
    float* h = H + row * 512;
    const int tid = threadIdx.x;
    float s0 = h[tid]       + (bias ? bias[tid]       : 0.0f);
    float s1 = h[tid + 256] + (bias ? bias[tid + 256] : 0.0f);
    for (int s = 0; s < ns; ++s) {
        const float* x = X + s * sstr + row * 512;
        s0 += x[tid];
        s1 += x[tid + 256];
    }
    float sum = s0 + s1, sq = s0 * s0 + s1 * s1;
#pragma unroll
    for (int o = 32; o > 0; o >>= 1) { sum += __shfl_down(sum, o, 64); sq += __shfl_down(sq, o, 64); }
    if ((tid & 63) == 0) { red[tid >> 6] = sum; red2[tid >> 6] = sq; }
    __syncthreads();
    sum = red[0] + red[1] + red[2] + red[3];
    sq  = red2[0] + red2[1] + red2[2] + red2[3];
    const float mu = sum * (1.0f / 512.0f);
    float var = sq * (1.0f / 512.0f) - mu * mu;
    var = fmaxf(var, 0.0f);
    const float rs = rsqrtf(var + 1e-5f);
    const float o0 = g[tid] * (s0 - mu) * rs + b[tid];
    const float o1 = g[tid + 256] * (s1 - mu) * rs + b[tid + 256];
    h[tid] = o0; h[tid + 256] = o1;
    Hf[row * 512 + tid]       = (f16_t)o0;
    Hf[row * 512 + tid + 256] = (f16_t)o1;
}

// ---------------- V_head [T,64] -> Vt [64,T] per (b,h) ----------------------
__global__ void vtrans_kernel(const f16_t* __restrict__ qkv, f16_t* __restrict__ Vt)
{
    __shared__ f16_t tl[32][34];
    const int z  = blockIdx.y;          // b*8 + h
    const int b  = z >> 3, hh = z & 7;
    const int tile = blockIdx.x;        // 0..31: 16 t-tiles x 2 c-tiles
    const int tr = tile >> 1, tc = tile & 1;
    const int t0 = tr * 32, c0 = tc * 32;
    const int tx = threadIdx.x, ty = threadIdx.y;
#pragma unroll
    for (int i = 0; i < 4; ++i)
        tl[ty + 8 * i][tx] = qkv[(long long)(b * 512 + t0 + ty + 8 * i) * 1536 + 1024 + hh * 64 + c0 + tx];
    __syncthreads();
#pragma unroll
    for (int i = 0; i < 4; ++i)
        Vt[((long long)z * 64 + c0 + ty + 8 * i) * 512 + t0 + tx] = tl[tx][ty + 8 * i];
}

// ---------------- classifier head: split reduction --------------------------
__global__ void head_partial_kernel(const float* __restrict__ h32, const float* __restrict__ Wout,
                                    float* __restrict__ partials)
{
    const int blk = blockIdx.x;         // 8 b * 64 chunks
    const int b = blk >> 6, chunk = blk & 63;
    const int tid = threadIdx.x;
    const float* hp = h32 + (long long)b * 262144 + (long long)chunk * 4096;
    float a0 = 0, a1 = 0, a2 = 0, a3 = 0, a4 = 0;
    for (int it = 0; it < 16; ++it) {
        const int idx = it * 256 + tid;
        const float hv = hp[idx];
        const float* w = Wout + ((long long)chunk * 4096 + idx) * 5;
        a0 += hv * w[0]; a1 += hv * w[1]; a2 += hv * w[2]; a3 += hv * w[3]; a4 += hv * w[4];
    }
#pragma unroll
    for (int o = 32; o > 0; o >>= 1) {
        a0 += __shfl_down(a0, o, 64); a1 += __shfl_down(a1, o, 64); a2 += __shfl_down(a2, o, 64);
        a3 += __shfl_down(a3, o, 64); a4 += __shfl_down(a4, o, 64);
    }
    __shared__ float sm[4][5];
    const int lane = tid & 63, w = tid >> 6;
    if (lane == 0) { sm[w][0] = a0; sm[w][1] = a1; sm[w][2] = a2; sm[w][3] = a3; sm[w][4] = a4; }
    __syncthreads();
    if (tid < 5)
        partials[(long long)blk * 5 + tid] = sm[0][tid] + sm[1][tid] + sm[2][tid] + sm[3][tid];
}

__global__ void head_final_kernel(const float* __restrict__ partials, const float* __restrict__ bout,
                                  float* __restrict__ out)
{
    const int tid = threadIdx.x;
    if (tid >= 40) return;
    const int b = tid / 5, c = tid % 5;
    float s = bout[c];
    const float* p = partials + (long long)b * 64 * 5 + c;
    for (int ck = 0; ck < 64; ++ck) s += p[ck * 5];
    out[tid] = s;   // reference output dtype is float32
}

// ---------------------------------------------------------------------------
extern "C" void kernel_launch(void* const* d_in, const int* in_sizes, int n_in,
                              void* d_out, int out_size, void* d_ws, size_t ws_size,
                              hipStream_t stream)
{
    (void)in_sizes; (void)n_in; (void)out_size; (void)ws_size;
    const int*   x_tok = (const int*)  d_in[0];
    const float* emb   = (const float*)d_in[2];
    const float* Wq    = (const float*)d_in[3];
    const float* bq    = (const float*)d_in[4];
    const float* Wk    = (const float*)d_in[5];
    const float* bk    = (const float*)d_in[6];
    const float* Wv    = (const float*)d_in[7];
    const float* bv    = (const float*)d_in[8];
    const float* Wo    = (const float*)d_in[9];
    const float* bo    = (const float*)d_in[10];
    const float* gma   = (const float*)d_in[11];
    const float* bta   = (const float*)d_in[12];
    const float* W1    = (const float*)d_in[13];
    const float* b1    = (const float*)d_in[14];
    const float* W2    = (const float*)d_in[15];
    const float* b2    = (const float*)d_in[16];
    const float* Wout  = (const float*)d_in[17];
    const float* bout  = (const float*)d_in[18];

    char* ws = (char*)d_ws;
    size_t off = 0;
    auto take = [&](size_t bytes) { char* p = ws + off; off += (bytes + 255) & ~(size_t)255; return p; };
    f16_t* wT    = (f16_t*)take(18874368ULL * 2);  // transposed f16 weights
    f16_t* hb    = (f16_t*)take(2097152ULL * 2);   // h, f16 copy
    f16_t* qkv   = (f16_t*)take(6291456ULL * 2);   // [4096][1536]
    f16_t* S     = (f16_t*)take(16777216ULL * 2);  // [64][512][512] scores/probs
    f16_t* Vt    = (f16_t*)take(2097152ULL * 2);   // [64][64][512]
    f16_t* ao    = (f16_t*)take(2097152ULL * 2);   // attn out [4096][512]
    f16_t* f1    = (f16_t*)take(8388608ULL * 2);   // ffn hidden [4096][2048]
    float* qkvb  = (float*)take(9216ULL * 4);
    float* h32   = (float*)take(2097152ULL * 4);   // residual stream f32
    float* t32   = (float*)take(4ULL * 2097152ULL * 4); // split-K partials (up to 4)
    float* parts = (float*)take(2560ULL * 4);

    wconv_kernel <<<dim3(18432), dim3(32, 8), 0, stream>>>(Wq, Wk, Wv, Wo, W1, W2, wT);
    biascat_kernel<<<dim3(36), 256, 0, stream>>>(bq, bk, bv, qkvb);
    embed_kernel <<<dim3(4096), 256, 0, stream>>>(x_tok, emb, h32, hb);

    for (int l = 0; l < 6; ++l) {
        const f16_t* wl = wT + (long long)l * LSTR;
        // QKV: [4096,512] @ [512,1536] -> qkv f16
        gemm_kernel<128,128,2,2,1,0><<<dim3(32,12,1),256,0,stream>>>(hb, wl, qkvb + l*1536, qkv,
            4096,1536,512, 512,512,1536, 1, 0,0,0,0,0,0);
        vtrans_kernel<<<dim3(32,64), dim3(32,8), 0, stream>>>(qkv, Vt);
        // scores: per (b,h): Q[512,64] @ K^T -> S f16
        gemm_kernel<128,128,2,2,1,0><<<dim3(4,4,64),256,0,stream>>>(qkv, qkv + 512, nullptr, S,
            512,512,64, 1536,1536,512, 8, 786432LL,64LL, 786432LL,64LL, 2097152LL,262144LL);
        softmax_kernel<<<dim3(32768),256,0,stream>>>(S);
        // PV: P[512,512] @ Vt^T[512,64] -> ao (cols h*64..), 64x64 tiles
        gemm_kernel<64,64,2,2,1,0><<<dim3(8,1,64),256,0,stream>>>(S, Vt, nullptr, ao,
            512,64,512, 512,512,512, 8, 2097152LL,262144LL, 262144LL,32768LL, 262144LL,64LL);
        // O proj, split-K x2 -> t32 partial slices [2][4096][512]
        gemm_kernel<128,128,2,2,0,0><<<dim3(32,4,2),256,0,stream>>>(ao, wl + 786432, nullptr, t32,
            4096,512,256, 512,512,512, 1, 256LL,0LL, 256LL,0LL, 2097152LL,0LL);
        add_ln_kernel<<<dim3(4096),256,0,stream>>>(t32, 2, 2097152LL, bo + l*512,
            h32, gma + l*512, bta + l*512, hb);
        // FFN1 + relu -> f1 f16
        gemm_kernel<128,128,2,2,1,1><<<dim3(32,16,1),256,0,stream>>>(hb, wl + 1048576, b1 + l*2048, f1,
            4096,2048,512, 512,512,2048, 1, 0,0,0,0,0,0);
        // FFN2, split-K x4 -> t32 partial slices [4][4096][512]
        gemm_kernel<128,128,2,2,0,0><<<dim3(32,4,4),256,0,stream>>>(f1, wl + 2097152, nullptr, t32,
            4096,512,512, 2048,2048,512, 1, 512LL,0LL, 512LL,0LL, 2097152LL,0LL);
        add_ln_kernel<<<dim3(4096),256,0,stream>>>(t32, 4, 2097152LL, b2 + l*512,
            h32, gma + l*512, bta + l*512, hb);
    }

    head_partial_kernel<<<dim3(512),256,0,stream>>>(h32, Wout, parts);
    head_final_kernel  <<<dim3(1),64,0,stream>>>(parts, bout, (float*)d_out);
}

// Round 4
// 720.272 us; speedup vs baseline: 1.7361x; 1.2210x over previous
//
#include <hip/hip_runtime.h>
#include <hip/hip_bf16.h>

// ---------------------------------------------------------------------------
// 6-layer transformer forward, MI355X. f16 MFMA compute, f32 accum/residuals.
// Round 4: softmax fused into PV (flash-style post-normalization), BM=64
//          tiles for occupancy, FFN2 split-K 4->2.
// ---------------------------------------------------------------------------

typedef _Float16 f16_t;
typedef _Float16 f16x8 __attribute__((ext_vector_type(8)));
typedef _Float16 f16x2 __attribute__((ext_vector_type(2)));
typedef float    f32x4 __attribute__((ext_vector_type(4)));

#define LSTR 3145728LL  // per-layer transposed-weight stride (f16 elems)

__device__ __forceinline__ void gl_lds16(const f16_t* g, f16_t* l) {
    __builtin_amdgcn_global_load_lds(
        (const __attribute__((address_space(1))) unsigned int*)g,
        (__attribute__((address_space(3))) unsigned int*)l, 16, 0, 0);
}

// ---------------- pipelined batched GEMM: C = A[M,K] * (Bt[N,K])^T + bias ---
// A, Bt f16 row-major. blockIdx.z -> zh=z/zmod, zl=z%zmod; per-operand strides.
// Split-K via zmod=1, sAhi/sBhi = K-slice offset, sChi = C-slice stride.
// LDS: linear dest (global_load_lds), XOR-swizzled k-chunk on BOTH the global
// source and the LDS read offset (rule #21).
template<int BM, int BN, int WR, int WC, int OUTF16, int RELU>
__global__ void __launch_bounds__(256)
gemm_kernel(const f16_t* __restrict__ A, const f16_t* __restrict__ B,
            const float* __restrict__ bias, void* __restrict__ Cout,
            int M, int N, int K, int lda, int ldb, int ldc, int zmod,
            long long sAhi, long long sAlo, long long sBhi, long long sBlo,
            long long sChi, long long sClo)
{
    constexpr int BK  = 32;
    constexpr int WMT = BM / WR;
    constexpr int WNT = BN / WC;
    constexpr int MR  = WMT / 16;
    constexpr int NR  = WNT / 16;
    constexpr int IA  = BM / 64;        // global_load_lds issues per thread (A)
    constexpr int IB  = BN / 64;
    __shared__ __align__(16) f16_t As[2][BM][BK];
    __shared__ __align__(16) f16_t Bs[2][BN][BK];

    const int tid  = threadIdx.x;
    const int wid  = tid >> 6, lane = tid & 63;
    const int wr   = wid / WC, wc = wid % WC;
    const int z    = blockIdx.z;
    const int zh   = z / zmod, zl = z % zmod;
    const f16_t* Ab = A + (long long)zh * sAhi + (long long)zl * sAlo;
    const f16_t* Bb = B + (long long)zh * sBhi + (long long)zl * sBlo;
    const int m0 = blockIdx.x * BM;
    const int n0 = blockIdx.y * BN;

    f32x4 acc[MR][NR] = {};

    // ---- staging addresses: chunk c = i*256+tid; row=c>>2, kchunk=(c&3)^swz
    const f16_t* srcA[IA]; const f16_t* srcB[IB];
#pragma unroll
    for (int i = 0; i < IA; ++i) {
        const int c = i * 256 + tid, row = c >> 2;
        const int kch = (c & 3) ^ ((row >> 1) & 3);
        srcA[i] = Ab + (long long)(m0 + row) * lda + kch * 8;
    }
#pragma unroll
    for (int i = 0; i < IB; ++i) {
        const int c = i * 256 + tid, row = c >> 2;
        const int kch = (c & 3) ^ ((row >> 1) & 3);
        srcB[i] = Bb + (long long)(n0 + row) * ldb + kch * 8;
    }
    auto stage = [&](int bf_, int t) {
        const int k0 = t * BK;
#pragma unroll
        for (int i = 0; i < IA; ++i)
            gl_lds16(srcA[i] + k0, &As[bf_][0][0] + (i * 256 + wid * 64) * 8);
#pragma unroll
        for (int i = 0; i < IB; ++i)
            gl_lds16(srcB[i] + k0, &Bs[bf_][0][0] + (i * 256 + wid * 64) * 8);
    };

    // ---- fragment read offsets (bytes), swizzled to match staged layout
    const int l15 = lane & 15;
    const int kc  = (lane >> 4) * 8;    // 8 contiguous k per lane
    int aoff[MR], boff[NR];
#pragma unroll
    for (int m = 0; m < MR; ++m) {
        const int row = wr * WMT + m * 16 + l15;
        aoff[m] = ((row * BK + kc) * 2) ^ (((row >> 1) & 3) << 4);
    }
#pragma unroll
    for (int n = 0; n < NR; ++n) {
        const int row = wc * WNT + n * 16 + l15;
        boff[n] = ((row * BK + kc) * 2) ^ (((row >> 1) & 3) << 4);
    }

    const int NT = K / BK;
    stage(0, 0);
    __syncthreads();                    // drains vmcnt before barrier

    int buf = 0;
    for (int t = 0; t < NT; ++t) {
        if (t + 1 < NT) stage(buf ^ 1, t + 1);   // loads fly during MFMA
        const char* Al = (const char*)&As[buf][0][0];
        const char* Bl = (const char*)&Bs[buf][0][0];
        f16x8 af[MR], bfr[NR];
#pragma unroll
        for (int m = 0; m < MR; ++m) af[m]  = *(const f16x8*)(Al + aoff[m]);
#pragma unroll
        for (int n = 0; n < NR; ++n) bfr[n] = *(const f16x8*)(Bl + boff[n]);
#pragma unroll
        for (int m = 0; m < MR; ++m)
#pragma unroll
            for (int n = 0; n < NR; ++n)
                acc[m][n] = __builtin_amdgcn_mfma_f32_16x16x32_f16(af[m], bfr[n], acc[m][n], 0, 0, 0);
        __syncthreads();                // drains vmcnt+lgkmcnt, swap safe
        buf ^= 1;
    }

    const long long cOff = (long long)zh * sChi + (long long)zl * sClo;
    const int rbase = (lane >> 4) * 4;  // C/D: row=(lane>>4)*4+r, col=lane&15
#pragma unroll
    for (int m = 0; m < MR; ++m) {
        const int row = m0 + wr * WMT + m * 16 + rbase;
#pragma unroll
        for (int n = 0; n < NR; ++n) {
            const int col = n0 + wc * WNT + n * 16 + l15;
            const float bb = bias ? bias[col] : 0.0f;
#pragma unroll
            for (int r = 0; r < 4; ++r) {
                float v = acc[m][n][r] + bb;
                if (RELU) v = fmaxf(v, 0.0f);
                const long long idx = cOff + (long long)(row + r) * ldc + col;
                if (OUTF16) ((f16_t*)Cout)[idx] = (f16_t)v;
                else        ((float*)Cout)[idx] = v;
            }
        }
    }
}

// ------- fused softmax(S) @ V per (b,h): raw S[64][512] -> ao[64][64] -------
// Unnormalized E = exp(s - rowmax) in LDS; O = (E @ V) * rowinv in epilogue.
__global__ void __launch_bounds__(256)
attn_pv_kernel(const f16_t* __restrict__ S, const f16_t* __restrict__ Vt,
               f16_t* __restrict__ ao)
{
    __shared__ __align__(16) f16_t Ps[64][512];   // 64KB, chunk ^= (row&7)
    __shared__ __align__(16) f16_t Bs[64][64];    // 8KB,  chunk ^= (n&7)
    __shared__ float rowinv[64];
    const int tid  = threadIdx.x;
    const int wid  = tid >> 6, lane = tid & 63;
    const int z    = blockIdx.y;        // b*8 + h
    const int m0   = blockIdx.x * 64;
    const f16_t* Sb = S  + (long long)z * 262144 + (long long)m0 * 512;
    const f16_t* Vb = Vt + (long long)z * 32768;

    // stage S tile (raw scores), inverse-swizzled source, linear LDS dest
#pragma unroll
    for (int i = 0; i < 16; ++i) {
        const int c = i * 256 + tid, row = c >> 6, j = c & 63;
        gl_lds16(Sb + row * 512 + ((j ^ (row & 7)) << 3),
                 &Ps[0][0] + (i * 256 + wid * 64) * 8);
    }
    __syncthreads();

    // softmax: 4 lanes per row; pass1 max, pass2 exp+writeback+sum
    const int srow = tid >> 2, ssub = tid & 3;
    float mx = -1e30f;
#pragma unroll
    for (int i = 0; i < 16; ++i) {
        const int j = i * 4 + ssub;
        const f16x8 v = *(const f16x8*)(&Ps[0][0] + srow * 512 + ((j ^ (srow & 7)) << 3));
#pragma unroll
        for (int e = 0; e < 8; ++e) mx = fmaxf(mx, (float)v[e]);
    }
    mx = fmaxf(mx, __shfl_xor(mx, 1, 64));
    mx = fmaxf(mx, __shfl_xor(mx, 2, 64));
    float sum = 0.0f;
#pragma unroll
    for (int i = 0; i < 16; ++i) {
        const int j = i * 4 + ssub;
        f16_t* p = &Ps[0][0] + srow * 512 + ((j ^ (srow & 7)) << 3);
        const f16x8 v = *(const f16x8*)p;
        f16x8 o;
#pragma unroll
        for (int e = 0; e < 8; ++e) {
            const float ex = __expf((float)v[e] - mx);
            sum += ex;
            o[e] = (f16_t)ex;
        }
        *(f16x8*)p = o;
    }
    sum += __shfl_xor(sum, 1, 64);
    sum += __shfl_xor(sum, 2, 64);
    if (ssub == 0) rowinv[srow] = 1.0f / sum;
    __syncthreads();

    // PV: E[64][512] @ Vt^T[512][64]; wave wid owns cols wid*16..wid*16+15
    const int l15 = lane & 15, kq = lane >> 4;
    f32x4 acc[4] = {};
    for (int t = 0; t < 8; ++t) {       // BK=64
        if (t) __syncthreads();         // previous Bs consumed
#pragma unroll
        for (int i = 0; i < 2; ++i) {
            const int c = i * 256 + tid, n = c >> 3, jj = c & 7;
            gl_lds16(Vb + n * 512 + t * 64 + ((jj ^ (n & 7)) << 3),
                     &Bs[0][0] + (i * 256 + wid * 64) * 8);
        }
        __syncthreads();                // vmcnt drained by barrier
        f16x8 bfr[2];
#pragma unroll
        for (int kk = 0; kk < 2; ++kk) {
            const int n = wid * 16 + l15;
            bfr[kk] = *(const f16x8*)(&Bs[0][0] + n * 64 + (((kk * 4 + kq) ^ (n & 7)) << 3));
        }
#pragma unroll
        for (int m = 0; m < 4; ++m) {
            const int row = m * 16 + l15;
#pragma unroll
            for (int kk = 0; kk < 2; ++kk) {
                const f16x8 af = *(const f16x8*)(&Ps[0][0] + row * 512 +
                                   (((t * 8 + kk * 4 + kq) ^ (row & 7)) << 3));
                acc[m] = __builtin_amdgcn_mfma_f32_16x16x32_f16(af, bfr[kk], acc[m], 0, 0, 0);
            }
        }
    }

    const int b = z >> 3, hh = z & 7;
    const int rbase = (lane >> 4) * 4;
#pragma unroll
    for (int m = 0; m < 4; ++m) {
#pragma unroll
        for (int r = 0; r < 4; ++r) {
            const int row = m * 16 + rbase + r;
            const float v = acc[m][r] * rowinv[row];
            ao[((long long)(b * 512 + m0 + row)) * 512 + hh * 64 + wid * 16 + l15] = (f16_t)v;
        }
    }
}

// ---------------- weight convert+transpose f32 -> f16, [K,N] -> [N,K] -------
__global__ void wconv_kernel(const float* __restrict__ Wq, const float* __restrict__ Wk,
                             const float* __restrict__ Wv, const float* __restrict__ Wo,
                             const float* __restrict__ W1, const float* __restrict__ W2,
                             f16_t* __restrict__ wT)
{
    __shared__ float tile[32][33];
    const int t     = blockIdx.x;       // 18432 tiles = 6 layers * 3072
    const int layer = t / 3072;
    const int r     = t % 3072;
    const float* src; f16_t* dst; int R, C, tt;
    if (r < 1024) {                     // Wq,Wk,Wv,Wo: [512,512]
        const int mat = r >> 8; tt = r & 255; R = 512; C = 512;
        const float* s4 = (mat == 0) ? Wq : (mat == 1) ? Wk : (mat == 2) ? Wv : Wo;
        src = s4 + (long long)layer * 262144;
        dst = wT + (long long)layer * LSTR + (long long)mat * 262144;
    } else if (r < 2048) {              // W1: [512,2048] -> [2048,512]
        tt = r - 1024; R = 512; C = 2048;
        src = W1 + (long long)layer * 1048576;
        dst = wT + (long long)layer * LSTR + 1048576;
    } else {                            // W2: [2048,512] -> [512,2048]
        tt = r - 2048; R = 2048; C = 512;
        src = W2 + (long long)layer * 1048576;
        dst = wT + (long long)layer * LSTR + 2097152;
    }
    const int tC = C >> 5;
    const int tr = tt / tC, tc = tt % tC;
    const int r0 = tr * 32, c0 = tc * 32;
    const int tx = threadIdx.x, ty = threadIdx.y;
#pragma unroll
    for (int i = 0; i < 4; ++i)
        tile[ty + 8 * i][tx] = src[(long long)(r0 + ty + 8 * i) * C + c0 + tx];
    __syncthreads();
#pragma unroll
    for (int i = 0; i < 4; ++i)
        dst[(long long)(c0 + ty + 8 * i) * R + r0 + tx] = (f16_t)tile[tx][ty + 8 * i];
}

// ---------------- concat per-layer [bq|bk|bv] -> [6][1536] ------------------
__global__ void biascat_kernel(const float* __restrict__ bq, const float* __restrict__ bk,
                               const float* __restrict__ bv, float* __restrict__ qkvb)
{
    const int i = blockIdx.x * 256 + threadIdx.x;
    if (i >= 9216) return;
    const int l = i / 1536, c = i % 1536;
    float v;
    if (c < 512)       v = bq[l * 512 + c];
    else if (c < 1024) v = bk[l * 512 + c - 512];
    else               v = bv[l * 512 + c - 1024];
    qkvb[i] = v;
}

// ---------------- embedding gather + sinusoidal PE --------------------------
__global__ void embed_kernel(const int* __restrict__ xt, const float* __restrict__ emb,
                             float* __restrict__ h32, f16_t* __restrict__ hb)
{
    const int row = blockIdx.x;         // b*512 + t
    const int t   = row & 511;
    const int tok = xt[row];
    const int tid = threadIdx.x;
#pragma unroll
    for (int s = 0; s < 2; ++s) {
        const int d = tid + s * 256;
        const int i = d >> 1;
        const float inv = expf((float)(2 * i) * (-9.210340371976184f / 512.0f));
        const float ang = (float)t * inv;
        const float pe  = (d & 1) ? cosf(ang) : sinf(ang);
        const float v   = emb[(long long)tok * 512 + d] + pe;
        h32[(long long)row * 512 + d] = v;
        hb [(long long)row * 512 + d] = (f16_t)v;
    }
}

// ------- h = LN( sum_{s<ns} X[s] + bias + h ); also write f16 copy ----------
__global__ void add_ln_kernel(const float* __restrict__ X, int ns, long long sstr,
                              const float* __restrict__ bias,
                              float* __restrict__ H,
                              const float* __restrict__ g, const float* __restrict__ b,
                              f16_t* __restrict__ Hf)
{
    __shared__ float red[4], red2[4];
    const long long row = blockIdx.x;
    float* h = H + row * 512;
    const int tid = threadIdx.x;
    float s0 = h[tid]       + (bias ? bias[tid]       : 0.0f);
    float s1 = h[tid + 256] + (bias ? bias[tid + 256] : 0.0f);
    for (int s = 0; s < ns; ++s) {
        const float* x = X + s * sstr + row * 512;
        s0 += x[tid];
        s1 += x[tid + 256];
    }
    float sum = s0 + s1, sq = s0 * s0 + s1 * s1;
#pragma unroll
    for (int o = 32; o > 0; o >>= 1) { sum += __shfl_down(sum, o, 64); sq += __shfl_down(sq, o, 64); }
    if ((tid & 63) == 0) { red[tid >> 6] = sum; red2[tid >> 6] = sq; }
    __syncthreads();
    sum = red[0] + red[1] + red[2] + red[3];
    sq  = red2[0] + red2[1] + red2[2] + red2[3];
    const float mu = sum * (1.0f / 512.0f);
    float var = sq * (1.0f / 512.0f) - mu * mu;
    var = fmaxf(var, 0.0f);
    const float rs = rsqrtf(var + 1e-5f);
    const float o0 = g[tid] * (s0 - mu) * rs + b[tid];
    const float o1 = g[tid + 256] * (s1 - mu) * rs + b[tid + 256];
    h[tid] = o0; h[tid + 256] = o1;
    Hf[row * 512 + tid]       = (f16_t)o0;
    Hf[row * 512 + tid + 256] = (f16_t)o1;
}

// ---------------- V_head [T,64] -> Vt [64,T] per (b,h) ----------------------
__global__ void vtrans_kernel(const f16_t* __restrict__ qkv, f16_t* __restrict__ Vt)
{
    __shared__ f16_t tl[32][34];
    const int z  = blockIdx.y;          // b*8 + h
    const int b  = z >> 3, hh = z & 7;
    const int tile = blockIdx.x;        // 0..31: 16 t-tiles x 2 c-tiles
    const int tr = tile >> 1, tc = tile & 1;
    const int t0 = tr * 32, c0 = tc * 32;
    const int tx = threadIdx.x, ty = threadIdx.y;
#pragma unroll
    for (int i = 0; i < 4; ++i)
        tl[ty + 8 * i][tx] = qkv[(long long)(b * 512 + t0 + ty + 8 * i) * 1536 + 1024 + hh * 64 + c0 + tx];
    __syncthreads();
#pragma unroll
    for (int i = 0; i < 4; ++i)
        Vt[((long long)z * 64 + c0 + ty + 8 * i) * 512 + t0 + tx] = tl[tx][ty + 8 * i];
}

// ---------------- classifier head: split reduction --------------------------
__global__ void head_partial_kernel(const float* __restrict__ h32, const float* __restrict__ Wout,
                                    float* __restrict__ partials)
{
    const int blk = blockIdx.x;         // 8 b * 64 chunks
    const int b = blk >> 6, chunk = blk & 63;
    const int tid = threadIdx.x;
    const float* hp = h32 + (long long)b * 262144 + (long long)chunk * 4096;
    float a0 = 0, a1 = 0, a2 = 0, a3 = 0, a4 = 0;
    for (int it = 0; it < 16; ++it) {
        const int idx = it * 256 + tid;
        const float hv = hp[idx];
        const float* w = Wout + ((long long)chunk * 4096 + idx) * 5;
        a0 += hv * w[0]; a1 += hv * w[1]; a2 += hv * w[2]; a3 += hv * w[3]; a4 += hv * w[4];
    }
#pragma unroll
    for (int o = 32; o > 0; o >>= 1) {
        a0 += __shfl_down(a0, o, 64); a1 += __shfl_down(a1, o, 64); a2 += __shfl_down(a2, o, 64);
        a3 += __shfl_down(a3, o, 64); a4 += __shfl_down(a4, o, 64);
    }
    __shared__ float sm[4][5];
    const int lane = tid & 63, w = tid >> 6;
    if (lane == 0) { sm[w][0] = a0; sm[w][1] = a1; sm[w][2] = a2; sm[w][3] = a3; sm[w][4] = a4; }
    __syncthreads();
    if (tid < 5)
        partials[(long long)blk * 5 + tid] = sm[0][tid] + sm[1][tid] + sm[2][tid] + sm[3][tid];
}

__global__ void head_final_kernel(const float* __restrict__ partials, const float* __restrict__ bout,
                                  float* __restrict__ out)
{
    const int tid = threadIdx.x;
    if (tid >= 40) return;
    const int b = tid / 5, c = tid % 5;
    float s = bout[c];
    const float* p = partials + (long long)b * 64 * 5 + c;
    for (int ck = 0; ck < 64; ++ck) s += p[ck * 5];
    out[tid] = s;   // reference output dtype is float32
}

// ---------------------------------------------------------------------------
extern "C" void kernel_launch(void* const* d_in, const int* in_sizes, int n_in,
                              void* d_out, int out_size, void* d_ws, size_t ws_size,
                              hipStream_t stream)
{
    (void)in_sizes; (void)n_in; (void)out_size; (void)ws_size;
    const int*   x_tok = (const int*)  d_in[0];
    const float* emb   = (const float*)d_in[2];
    const float* Wq    = (const float*)d_in[3];
    const float* bq    = (const float*)d_in[4];
    const float* Wk    = (const float*)d_in[5];
    const float* bk    = (const float*)d_in[6];
    const float* Wv    = (const float*)d_in[7];
    const float* bv    = (const float*)d_in[8];
    const float* Wo    = (const float*)d_in[9];
    const float* bo    = (const float*)d_in[10];
    const float* gma   = (const float*)d_in[11];
    const float* bta   = (const float*)d_in[12];
    const float* W1    = (const float*)d_in[13];
    const float* b1    = (const float*)d_in[14];
    const float* W2    = (const float*)d_in[15];
    const float* b2    = (const float*)d_in[16];
    const float* Wout  = (const float*)d_in[17];
    const float* bout  = (const float*)d_in[18];

    char* ws = (char*)d_ws;
    size_t off = 0;
    auto take = [&](size_t bytes) { char* p = ws + off; off += (bytes + 255) & ~(size_t)255; return p; };
    f16_t* wT    = (f16_t*)take(18874368ULL * 2);  // transposed f16 weights
    f16_t* hb    = (f16_t*)take(2097152ULL * 2);   // h, f16 copy
    f16_t* qkv   = (f16_t*)take(6291456ULL * 2);   // [4096][1536]
    f16_t* S     = (f16_t*)take(16777216ULL * 2);  // [64][512][512] raw scores
    f16_t* Vt    = (f16_t*)take(2097152ULL * 2);   // [64][64][512]
    f16_t* ao    = (f16_t*)take(2097152ULL * 2);   // attn out [4096][512]
    f16_t* f1    = (f16_t*)take(8388608ULL * 2);   // ffn hidden [4096][2048]
    float* qkvb  = (float*)take(9216ULL * 4);
    float* h32   = (float*)take(2097152ULL * 4);   // residual stream f32
    float* t32   = (float*)take(4ULL * 2097152ULL * 4); // split-K partials
    float* parts = (float*)take(2560ULL * 4);

    wconv_kernel <<<dim3(18432), dim3(32, 8), 0, stream>>>(Wq, Wk, Wv, Wo, W1, W2, wT);
    biascat_kernel<<<dim3(36), 256, 0, stream>>>(bq, bk, bv, qkvb);
    embed_kernel <<<dim3(4096), 256, 0, stream>>>(x_tok, emb, h32, hb);

    for (int l = 0; l < 6; ++l) {
        const f16_t* wl = wT + (long long)l * LSTR;
        // QKV: [4096,512] @ [512,1536] -> qkv f16 (768 blocks, 3/CU)
        gemm_kernel<64,128,2,2,1,0><<<dim3(64,12,1),256,0,stream>>>(hb, wl, qkvb + l*1536, qkv,
            4096,1536,512, 512,512,1536, 1, 0,0,0,0,0,0);
        vtrans_kernel<<<dim3(32,64), dim3(32,8), 0, stream>>>(qkv, Vt);
        // scores: per (b,h): Q[512,64] @ K^T -> S f16 (raw, softmax fused in PV)
        gemm_kernel<128,128,2,2,1,0><<<dim3(4,4,64),256,0,stream>>>(qkv, qkv + 512, nullptr, S,
            512,512,64, 1536,1536,512, 8, 786432LL,64LL, 786432LL,64LL, 2097152LL,262144LL);
        // fused softmax + PV -> ao
        attn_pv_kernel<<<dim3(8,64),256,0,stream>>>(S, Vt, ao);
        // O proj, split-K x2 -> t32 partial slices [2][4096][512]
        gemm_kernel<64,128,2,2,0,0><<<dim3(64,4,2),256,0,stream>>>(ao, wl + 786432, nullptr, t32,
            4096,512,256, 512,512,512, 1, 256LL,0LL, 256LL,0LL, 2097152LL,0LL);
        add_ln_kernel<<<dim3(4096),256,0,stream>>>(t32, 2, 2097152LL, bo + l*512,
            h32, gma + l*512, bta + l*512, hb);
        // FFN1 + relu -> f1 f16 (1024 blocks, 4/CU)
        gemm_kernel<64,128,2,2,1,1><<<dim3(64,16,1),256,0,stream>>>(hb, wl + 1048576, b1 + l*2048, f1,
            4096,2048,512, 512,512,2048, 1, 0,0,0,0,0,0);
        // FFN2, split-K x2 -> t32 partial slices [2][4096][512]
        gemm_kernel<64,128,2,2,0,0><<<dim3(64,4,2),256,0,stream>>>(f1, wl + 2097152, nullptr, t32,
            4096,512,1024, 2048,2048,512, 1, 1024LL,0LL, 1024LL,0LL, 2097152LL,0LL);
        add_ln_kernel<<<dim3(4096),256,0,stream>>>(t32, 2, 2097152LL, b2 + l*512,
            h32, gma + l*512, bta + l*512, hb);
    }

    head_partial_kernel<<<dim3(512),256,0,stream>>>(h32, Wout, parts);
    head_final_kernel  <<<dim3(1),64,0,stream>>>(parts, bout, (float*)d_out);
}

// Round 5
// 695.451 us; speedup vs baseline: 1.7981x; 1.0357x over previous
//
#include <hip/hip_runtime.h>
#include <hip/hip_bf16.h>

// ---------------------------------------------------------------------------
// 6-layer transformer forward, MI355X. f16 MFMA compute, f32 accum/residuals.
// Round 5: single-kernel flash attention (S never hits HBM), de-split
//          O-proj/FFN2 (64x64 tiles), FFN1 back to 128x128.
// ---------------------------------------------------------------------------

typedef _Float16 f16_t;
typedef _Float16 f16x8 __attribute__((ext_vector_type(8)));
typedef _Float16 f16x4 __attribute__((ext_vector_type(4)));
typedef _Float16 f16x2 __attribute__((ext_vector_type(2)));
typedef float    f32x4 __attribute__((ext_vector_type(4)));

#define LSTR 3145728LL  // per-layer transposed-weight stride (f16 elems)

__device__ __forceinline__ void gl_lds16(const f16_t* g, f16_t* l) {
    __builtin_amdgcn_global_load_lds(
        (const __attribute__((address_space(1))) unsigned int*)g,
        (__attribute__((address_space(3))) unsigned int*)l, 16, 0, 0);
}

// ---------------- pipelined batched GEMM: C = A[M,K] * (Bt[N,K])^T + bias ---
// A, Bt f16 row-major. blockIdx.z -> zh=z/zmod, zl=z%zmod; per-operand strides.
// LDS: linear dest (global_load_lds), XOR-swizzled k-chunk on BOTH the global
// source and the LDS read offset (rule #21).
template<int BM, int BN, int WR, int WC, int OUTF16, int RELU>
__global__ void __launch_bounds__(256)
gemm_kernel(const f16_t* __restrict__ A, const f16_t* __restrict__ B,
            const float* __restrict__ bias, void* __restrict__ Cout,
            int M, int N, int K, int lda, int ldb, int ldc, int zmod,
            long long sAhi, long long sAlo, long long sBhi, long long sBlo,
            long long sChi, long long sClo)
{
    constexpr int BK  = 32;
    constexpr int WMT = BM / WR;
    constexpr int WNT = BN / WC;
    constexpr int MR  = WMT / 16;
    constexpr int NR  = WNT / 16;
    constexpr int IA  = BM / 64;        // global_load_lds issues per thread (A)
    constexpr int IB  = BN / 64;
    __shared__ __align__(16) f16_t As[2][BM][BK];
    __shared__ __align__(16) f16_t Bs[2][BN][BK];

    const int tid  = threadIdx.x;
    const int wid  = tid >> 6, lane = tid & 63;
    const int wr   = wid / WC, wc = wid % WC;
    const int z    = blockIdx.z;
    const int zh   = z / zmod, zl = z % zmod;
    const f16_t* Ab = A + (long long)zh * sAhi + (long long)zl * sAlo;
    const f16_t* Bb = B + (long long)zh * sBhi + (long long)zl * sBlo;
    const int m0 = blockIdx.x * BM;
    const int n0 = blockIdx.y * BN;

    f32x4 acc[MR][NR] = {};

    // ---- staging addresses: chunk c = i*256+tid; row=c>>2, kchunk=(c&3)^swz
    const f16_t* srcA[IA]; const f16_t* srcB[IB];
#pragma unroll
    for (int i = 0; i < IA; ++i) {
        const int c = i * 256 + tid, row = c >> 2;
        const int kch = (c & 3) ^ ((row >> 1) & 3);
        srcA[i] = Ab + (long long)(m0 + row) * lda + kch * 8;
    }
#pragma unroll
    for (int i = 0; i < IB; ++i) {
        const int c = i * 256 + tid, row = c >> 2;
        const int kch = (c & 3) ^ ((row >> 1) & 3);
        srcB[i] = Bb + (long long)(n0 + row) * ldb + kch * 8;
    }
    auto stage = [&](int bf_, int t) {
        const int k0 = t * BK;
#pragma unroll
        for (int i = 0; i < IA; ++i)
            gl_lds16(srcA[i] + k0, &As[bf_][0][0] + (i * 256 + wid * 64) * 8);
#pragma unroll
        for (int i = 0; i < IB; ++i)
            gl_lds16(srcB[i] + k0, &Bs[bf_][0][0] + (i * 256 + wid * 64) * 8);
    };

    // ---- fragment read offsets (bytes), swizzled to match staged layout
    const int l15 = lane & 15;
    const int kc  = (lane >> 4) * 8;    // 8 contiguous k per lane
    int aoff[MR], boff[NR];
#pragma unroll
    for (int m = 0; m < MR; ++m) {
        const int row = wr * WMT + m * 16 + l15;
        aoff[m] = ((row * BK + kc) * 2) ^ (((row >> 1) & 3) << 4);
    }
#pragma unroll
    for (int n = 0; n < NR; ++n) {
        const int row = wc * WNT + n * 16 + l15;
        boff[n] = ((row * BK + kc) * 2) ^ (((row >> 1) & 3) << 4);
    }

    const int NT = K / BK;
    stage(0, 0);
    __syncthreads();                    // drains vmcnt before barrier

    int buf = 0;
    for (int t = 0; t < NT; ++t) {
        if (t + 1 < NT) stage(buf ^ 1, t + 1);   // loads fly during MFMA
        const char* Al = (const char*)&As[buf][0][0];
        const char* Bl = (const char*)&Bs[buf][0][0];
        f16x8 af[MR], bfr[NR];
#pragma unroll
        for (int m = 0; m < MR; ++m) af[m]  = *(const f16x8*)(Al + aoff[m]);
#pragma unroll
        for (int n = 0; n < NR; ++n) bfr[n] = *(const f16x8*)(Bl + boff[n]);
#pragma unroll
        for (int m = 0; m < MR; ++m)
#pragma unroll
            for (int n = 0; n < NR; ++n)
                acc[m][n] = __builtin_amdgcn_mfma_f32_16x16x32_f16(af[m], bfr[n], acc[m][n], 0, 0, 0);
        __syncthreads();                // drains vmcnt+lgkmcnt, swap safe
        buf ^= 1;
    }

    const long long cOff = (long long)zh * sChi + (long long)zl * sClo;
    const int rbase = (lane >> 4) * 4;  // C/D: row=(lane>>4)*4+r, col=lane&15
#pragma unroll
    for (int m = 0; m < MR; ++m) {
        const int row = m0 + wr * WMT + m * 16 + rbase;
#pragma unroll
        for (int n = 0; n < NR; ++n) {
            const int col = n0 + wc * WNT + n * 16 + l15;
            const float bb = bias ? bias[col] : 0.0f;
#pragma unroll
            for (int r = 0; r < 4; ++r) {
                float v = acc[m][n][r] + bb;
                if (RELU) v = fmaxf(v, 0.0f);
                const long long idx = cOff + (long long)(row + r) * ldc + col;
                if (OUTF16) ((f16_t*)Cout)[idx] = (f16_t)v;
                else        ((float*)Cout)[idx] = v;
            }
        }
    }
}

// ------- flash attention per (b,h, 64-q tile): softmax(Q K^T) V -> ao -------
// K resident in LDS (swizzled); Q fragments hoisted; S^T computed as
// mfma(K, Q) so softmax state is per q=lane&15; P round-trips through a
// per-wave LDS buffer (b64 writes, b128 A-frag reads); V frags from global
// (L2-resident Vt). Online softmax, no barriers in the key loop.
__global__ void __launch_bounds__(256)
attn_flash_kernel(const f16_t* __restrict__ qkv, const f16_t* __restrict__ Vt,
                  f16_t* __restrict__ ao)
{
    __shared__ __align__(16) f16_t Ks[512 * 64];   // 64KB
    __shared__ __align__(16) f16_t Qs[64 * 64];    //  8KB
    __shared__ __align__(16) f16_t Ps[4][16 * 64]; //  8KB (per-wave private)
    const int tid = threadIdx.x, wid = tid >> 6, lane = tid & 63;
    const int l15 = lane & 15, g = lane >> 4;
    const int z = blockIdx.y, b = z >> 3, hh = z & 7;
    const int q0 = blockIdx.x * 64;
    const f16_t* Kbase = qkv + (long long)b * 512 * 1536 + 512 + hh * 64;
    const f16_t* Qbase = qkv + (long long)(b * 512 + q0) * 1536 + hh * 64;
    const f16_t* Vbase = Vt + (long long)z * 32768;

    // stage K[512][64] and Q[64][64]; linear LDS dest, inverse-swizzled source
#pragma unroll
    for (int i = 0; i < 16; ++i) {
        const int c = i * 256 + tid, t = c >> 3, j = c & 7;
        gl_lds16(Kbase + (long long)t * 1536 + ((j ^ (t & 7)) << 3), Ks + c * 8);
    }
#pragma unroll
    for (int i = 0; i < 2; ++i) {
        const int c = i * 256 + tid, t = c >> 3, j = c & 7;
        gl_lds16(Qbase + (long long)t * 1536 + ((j ^ (t & 7)) << 3), Qs + c * 8);
    }
    __syncthreads();

    // hoisted Q B-frags: this wave's q rows = wid*16 + l15
    const int q = wid * 16 + l15;
    f16x8 qf[2];
#pragma unroll
    for (int k = 0; k < 2; ++k)
        qf[k] = *(const f16x8*)(Qs + q * 64 + (((k * 4 + g) ^ (l15 & 7)) << 3));

    f32x4 ov[4] = {};                   // O rows q=g*4+r, cols dv=n*16+l15
    float m_run = -1e30f, l_run = 0.0f;
    f16_t* Pw = &Ps[wid][0];

    for (int ck = 0; ck < 8; ++ck) {
        const int kc0 = ck * 64;
        // V fragments for this key chunk (global, L2-resident)
        f16x8 vf[4][2];
#pragma unroll
        for (int n = 0; n < 4; ++n)
#pragma unroll
            for (int k = 0; k < 2; ++k)
                vf[n][k] = *(const f16x8*)(Vbase + (n * 16 + l15) * 512 + kc0 + k * 32 + g * 8);
        // S^T = K_chunk . Q^T : rows=keys, cols=q
        f32x4 s[4] = {};
#pragma unroll
        for (int k = 0; k < 2; ++k)
#pragma unroll
            for (int m = 0; m < 4; ++m) {
                const int key = kc0 + m * 16 + l15;
                const f16x8 a = *(const f16x8*)(Ks + key * 64 + (((k * 4 + g) ^ (key & 7)) << 3));
                s[m] = __builtin_amdgcn_mfma_f32_16x16x32_f16(a, qf[k], s[m], 0, 0, 0);
            }
        // online softmax over keys for q = l15
        float cmax = -1e30f;
#pragma unroll
        for (int m = 0; m < 4; ++m)
#pragma unroll
            for (int r = 0; r < 4; ++r) cmax = fmaxf(cmax, s[m][r]);
        cmax = fmaxf(cmax, __shfl_xor(cmax, 16, 64));
        cmax = fmaxf(cmax, __shfl_xor(cmax, 32, 64));
        const float mnew = fmaxf(m_run, cmax);
        const float corr = __expf(m_run - mnew);
        float csum = 0.0f;
#pragma unroll
        for (int m = 0; m < 4; ++m) {
            f16x4 p4;
#pragma unroll
            for (int r = 0; r < 4; ++r) {
                const float pe = __expf(s[m][r] - mnew);
                csum += pe;
                p4[r] = (f16_t)pe;
            }
            // P[q=l15][key=m*16+g*4+r], bank-swizzled at 16B granularity
            *(f16x4*)(Pw + l15 * 64 + ((((m * 2 + (g >> 1)) ^ (l15 & 7))) << 3) + ((g & 1) << 2)) = p4;
        }
        csum += __shfl_xor(csum, 16, 64);
        csum += __shfl_xor(csum, 32, 64);
        l_run = l_run * corr + csum;
        m_run = mnew;
        // rescale O (rows q=g*4+r) by corr (held at lane q)
        float cr[4];
#pragma unroll
        for (int r = 0; r < 4; ++r) cr[r] = __shfl(corr, g * 4 + r, 64);
#pragma unroll
        for (int n = 0; n < 4; ++n)
#pragma unroll
            for (int r = 0; r < 4; ++r) ov[n][r] *= cr[r];
        // PV: O += P . V
#pragma unroll
        for (int k = 0; k < 2; ++k) {
            const f16x8 pf = *(const f16x8*)(Pw + l15 * 64 + (((k * 4 + g) ^ (l15 & 7)) << 3));
#pragma unroll
            for (int n = 0; n < 4; ++n)
                ov[n] = __builtin_amdgcn_mfma_f32_16x16x32_f16(pf, vf[n][k], ov[n], 0, 0, 0);
        }
    }

    const float inv = 1.0f / l_run;
    float ir[4];
#pragma unroll
    for (int r = 0; r < 4; ++r) ir[r] = __shfl(inv, g * 4 + r, 64);
#pragma unroll
    for (int n = 0; n < 4; ++n)
#pragma unroll
        for (int r = 0; r < 4; ++r) {
            const long long row = b * 512 + q0 + wid * 16 + g * 4 + r;
            ao[row * 512 + hh * 64 + n * 16 + l15] = (f16_t)(ov[n][r] * ir[r]);
        }
}

// ---------------- weight convert+transpose f32 -> f16, [K,N] -> [N,K] -------
__global__ void wconv_kernel(const float* __restrict__ Wq, const float* __restrict__ Wk,
                             const float* __restrict__ Wv, const float* __restrict__ Wo,
                             const float* __restrict__ W1, const float* __restrict__ W2,
                             f16_t* __restrict__ wT)
{
    __shared__ float tile[32][33];
    const int t     = blockIdx.x;       // 18432 tiles = 6 layers * 3072
    const int layer = t / 3072;
    const int r     = t % 3072;
    const float* src; f16_t* dst; int R, C, tt;
    if (r < 1024) {                     // Wq,Wk,Wv,Wo: [512,512]
        const int mat = r >> 8; tt = r & 255; R = 512; C = 512;
        const float* s4 = (mat == 0) ? Wq : (mat == 1) ? Wk : (mat == 2) ? Wv : Wo;
        src = s4 + (long long)layer * 262144;
        dst = wT + (long long)layer * LSTR + (long long)mat * 262144;
    } else if (r < 2048) {              // W1: [512,2048] -> [2048,512]
        tt = r - 1024; R = 512; C = 2048;
        src = W1 + (long long)layer * 1048576;
        dst = wT + (long long)layer * LSTR + 1048576;
    } else {                            // W2: [2048,512] -> [512,2048]
        tt = r - 2048; R = 2048; C = 512;
        src = W2 + (long long)layer * 1048576;
        dst = wT + (long long)layer * LSTR + 2097152;
    }
    const int tC = C >> 5;
    const int tr = tt / tC, tc = tt % tC;
    const int r0 = tr * 32, c0 = tc * 32;
    const int tx = threadIdx.x, ty = threadIdx.y;
#pragma unroll
    for (int i = 0; i < 4; ++i)
        tile[ty + 8 * i][tx] = src[(long long)(r0 + ty + 8 * i) * C + c0 + tx];
    __syncthreads();
#pragma unroll
    for (int i = 0; i < 4; ++i)
        dst[(long long)(c0 + ty + 8 * i) * R + r0 + tx] = (f16_t)tile[tx][ty + 8 * i];
}

// ---------------- concat per-layer [bq|bk|bv] -> [6][1536] ------------------
__global__ void biascat_kernel(const float* __restrict__ bq, const float* __restrict__ bk,
                               const float* __restrict__ bv, float* __restrict__ qkvb)
{
    const int i = blockIdx.x * 256 + threadIdx.x;
    if (i >= 9216) return;
    const int l = i / 1536, c = i % 1536;
    float v;
    if (c < 512)       v = bq[l * 512 + c];
    else if (c < 1024) v = bk[l * 512 + c - 512];
    else               v = bv[l * 512 + c - 1024];
    qkvb[i] = v;
}

// ---------------- embedding gather + sinusoidal PE --------------------------
__global__ void embed_kernel(const int* __restrict__ xt, const float* __restrict__ emb,
                             float* __restrict__ h32, f16_t* __restrict__ hb)
{
    const int row = blockIdx.x;         // b*512 + t
    const int t   = row & 511;
    const int tok = xt[row];
    const int tid = threadIdx.x;
#pragma unroll
    for (int s = 0; s < 2; ++s) {
        const int d = tid + s * 256;
        const int i = d >> 1;
        const float inv = expf((float)(2 * i) * (-9.210340371976184f / 512.0f));
        const float ang = (float)t * inv;
        const float pe  = (d & 1) ? cosf(ang) : sinf(ang);
        const float v   = emb[(long long)tok * 512 + d] + pe;
        h32[(long long)row * 512 + d] = v;
        hb [(long long)row * 512 + d] = (f16_t)v;
    }
}

// ------- h = LN( sum_{s<ns} X[s] + bias + h ); also write f16 copy ----------
__global__ void add_ln_kernel(const float* __restrict__ X, int ns, long long sstr,
                              const float* __restrict__ bias,
                              float* __restrict__ H,
                              const float* __restrict__ g, const float* __restrict__ b,
                              f16_t* __restrict__ Hf)
{
    __shared__ float red[4], red2[4];
    const long long row = blockIdx.x;
    float* h = H + row * 512;
    const int tid = threadIdx.x;
    float s0 = h[tid]       + (bias ? bias[tid]       : 0.0f);
    float s1 = h[tid + 256] + (bias ? bias[tid + 256] : 0.0f);
    for (int s = 0; s < ns; ++s) {
        const float* x = X + s * sstr + row * 512;
        s0 += x[tid];
        s1 += x[tid + 256];
    }
    float sum = s0 + s1, sq = s0 * s0 + s1 * s1;
#pragma unroll
    for (int o = 32; o > 0; o >>= 1) { sum += __shfl_down(sum, o, 64); sq += __shfl_down(sq, o, 64); }
    if ((tid & 63) == 0) { red[tid >> 6] = sum; red2[tid >> 6] = sq; }
    __syncthreads();
    sum = red[0] + red[1] + red[2] + red[3];
    sq  = red2[0] + red2[1] + red2[2] + red2[3];
    const float mu = sum * (1.0f / 512.0f);
    float var = sq * (1.0f / 512.0f) - mu * mu;
    var = fmaxf(var, 0.0f);
    const float rs = rsqrtf(var + 1e-5f);
    const float o0 = g[tid] * (s0 - mu) * rs + b[tid];
    const float o1 = g[tid + 256] * (s1 - mu) * rs + b[tid + 256];
    h[tid] = o0; h[tid + 256] = o1;
    Hf[row * 512 + tid]       = (f16_t)o0;
    Hf[row * 512 + tid + 256] = (f16_t)o1;
}

// ---------------- V_head [T,64] -> Vt [64,T] per (b,h) ----------------------
__global__ void vtrans_kernel(const f16_t* __restrict__ qkv, f16_t* __restrict__ Vt)
{
    __shared__ f16_t tl[32][34];
    const int z  = blockIdx.y;          // b*8 + h
    const int b  = z >> 3, hh = z & 7;
    const int tile = blockIdx.x;        // 0..31: 16 t-tiles x 2 c-tiles
    const int tr = tile >> 1, tc = tile & 1;
    const int t0 = tr * 32, c0 = tc * 32;
    const int tx = threadIdx.x, ty = threadIdx.y;
#pragma unroll
    for (int i = 0; i < 4; ++i)
        tl[ty + 8 * i][tx] = qkv[(long long)(b * 512 + t0 + ty + 8 * i) * 1536 + 1024 + hh * 64 + c0 + tx];
    __syncthreads();
#pragma unroll
    for (int i = 0; i < 4; ++i)
        Vt[((long long)z * 64 + c0 + ty + 8 * i) * 512 + t0 + tx] = tl[tx][ty + 8 * i];
}

// ---------------- classifier head: split reduction --------------------------
__global__ void head_partial_kernel(const float* __restrict__ h32, const float* __restrict__ Wout,
                                    float* __restrict__ partials)
{
    const int blk = blockIdx.x;         // 8 b * 64 chunks
    const int b = blk >> 6, chunk = blk & 63;
    const int tid = threadIdx.x;
    const float* hp = h32 + (long long)b * 262144 + (long long)chunk * 4096;
    float a0 = 0, a1 = 0, a2 = 0, a3 = 0, a4 = 0;
    for (int it = 0; it < 16; ++it) {
        const int idx = it * 256 + tid;
        const float hv = hp[idx];
        const float* w = Wout + ((long long)chunk * 4096 + idx) * 5;
        a0 += hv * w[0]; a1 += hv * w[1]; a2 += hv * w[2]; a3 += hv * w[3]; a4 += hv * w[4];
    }
#pragma unroll
    for (int o = 32; o > 0; o >>= 1) {
        a0 += __shfl_down(a0, o, 64); a1 += __shfl_down(a1, o, 64); a2 += __shfl_down(a2, o, 64);
        a3 += __shfl_down(a3, o, 64); a4 += __shfl_down(a4, o, 64);
    }
    __shared__ float sm[4][5];
    const int lane = tid & 63, w = tid >> 6;
    if (lane == 0) { sm[w][0] = a0; sm[w][1] = a1; sm[w][2] = a2; sm[w][3] = a3; sm[w][4] = a4; }
    __syncthreads();
    if (tid < 5)
        partials[(long long)blk * 5 + tid] = sm[0][tid] + sm[1][tid] + sm[2][tid] + sm[3][tid];
}

__global__ void head_final_kernel(const float* __restrict__ partials, const float* __restrict__ bout,
                                  float* __restrict__ out)
{
    const int tid = threadIdx.x;
    if (tid >= 40) return;
    const int b = tid / 5, c = tid % 5;
    float s = bout[c];
    const float* p = partials + (long long)b * 64 * 5 + c;
    for (int ck = 0; ck < 64; ++ck) s += p[ck * 5];
    out[tid] = s;   // reference output dtype is float32
}

// ---------------------------------------------------------------------------
extern "C" void kernel_launch(void* const* d_in, const int* in_sizes, int n_in,
                              void* d_out, int out_size, void* d_ws, size_t ws_size,
                              hipStream_t stream)
{
    (void)in_sizes; (void)n_in; (void)out_size; (void)ws_size;
    const int*   x_tok = (const int*)  d_in[0];
    const float* emb   = (const float*)d_in[2];
    const float* Wq    = (const float*)d_in[3];
    const float* bq    = (const float*)d_in[4];
    const float* Wk    = (const float*)d_in[5];
    const float* bk    = (const float*)d_in[6];
    const float* Wv    = (const float*)d_in[7];
    const float* bv    = (const float*)d_in[8];
    const float* Wo    = (const float*)d_in[9];
    const float* bo    = (const float*)d_in[10];
    const float* gma   = (const float*)d_in[11];
    const float* bta   = (const float*)d_in[12];
    const float* W1    = (const float*)d_in[13];
    const float* b1    = (const float*)d_in[14];
    const float* W2    = (const float*)d_in[15];
    const float* b2    = (const float*)d_in[16];
    const float* Wout  = (const float*)d_in[17];
    const float* bout  = (const float*)d_in[18];

    char* ws = (char*)d_ws;
    size_t off = 0;
    auto take = [&](size_t bytes) { char* p = ws + off; off += (bytes + 255) & ~(size_t)255; return p; };
    f16_t* wT    = (f16_t*)take(18874368ULL * 2);  // transposed f16 weights
    f16_t* hb    = (f16_t*)take(2097152ULL * 2);   // h, f16 copy
    f16_t* qkv   = (f16_t*)take(6291456ULL * 2);   // [4096][1536]
    f16_t* Vt    = (f16_t*)take(2097152ULL * 2);   // [64][64][512]
    f16_t* ao    = (f16_t*)take(2097152ULL * 2);   // attn out [4096][512]
    f16_t* f1    = (f16_t*)take(8388608ULL * 2);   // ffn hidden [4096][2048]
    float* qkvb  = (float*)take(9216ULL * 4);
    float* h32   = (float*)take(2097152ULL * 4);   // residual stream f32
    float* t32   = (float*)take(2097152ULL * 4);   // pre-LN branch f32
    float* parts = (float*)take(2560ULL * 4);

    wconv_kernel <<<dim3(18432), dim3(32, 8), 0, stream>>>(Wq, Wk, Wv, Wo, W1, W2, wT);
    biascat_kernel<<<dim3(36), 256, 0, stream>>>(bq, bk, bv, qkvb);
    embed_kernel <<<dim3(4096), 256, 0, stream>>>(x_tok, emb, h32, hb);

    for (int l = 0; l < 6; ++l) {
        const f16_t* wl = wT + (long long)l * LSTR;
        // QKV: [4096,512] @ [512,1536] -> qkv f16 (768 blocks, 3/CU)
        gemm_kernel<64,128,2,2,1,0><<<dim3(64,12,1),256,0,stream>>>(hb, wl, qkvb + l*1536, qkv,
            4096,1536,512, 512,512,1536, 1, 0,0,0,0,0,0);
        vtrans_kernel<<<dim3(32,64), dim3(32,8), 0, stream>>>(qkv, Vt);
        // flash attention: softmax(QK^T)V -> ao, S never materialized
        attn_flash_kernel<<<dim3(8,64),256,0,stream>>>(qkv, Vt, ao);
        // O proj (no split) -> t32 f32, 64x64 tiles (512 blocks, 2/CU)
        gemm_kernel<64,64,2,2,0,0><<<dim3(64,8,1),256,0,stream>>>(ao, wl + 786432, nullptr, t32,
            4096,512,512, 512,512,512, 1, 0,0,0,0,0,0);
        add_ln_kernel<<<dim3(4096),256,0,stream>>>(t32, 1, 0LL, bo + l*512,
            h32, gma + l*512, bta + l*512, hb);
        // FFN1 + relu -> f1 f16, 128x128 tiles (512 blocks, 2/CU)
        gemm_kernel<128,128,2,2,1,1><<<dim3(32,16,1),256,0,stream>>>(hb, wl + 1048576, b1 + l*2048, f1,
            4096,2048,512, 512,512,2048, 1, 0,0,0,0,0,0);
        // FFN2 (no split) -> t32 f32, 64x64 tiles
        gemm_kernel<64,64,2,2,0,0><<<dim3(64,8,1),256,0,stream>>>(f1, wl + 2097152, nullptr, t32,
            4096,512,2048, 2048,2048,512, 1, 0,0,0,0,0,0);
        add_ln_kernel<<<dim3(4096),256,0,stream>>>(t32, 1, 0LL, b2 + l*512,
            h32, gma + l*512, bta + l*512, hb);
    }

    head_partial_kernel<<<dim3(512),256,0,stream>>>(h32, Wout, parts);
    head_final_kernel  <<<dim3(1),64,0,stream>>>(parts, bout, (float*)d_out);
}

// Round 6
// 624.456 us; speedup vs baseline: 2.0025x; 1.1137x over previous
//
#include <hip/hip_runtime.h>
#include <hip/hip_bf16.h>

// ---------------------------------------------------------------------------
// 6-layer transformer forward, MI355X. f16 MFMA compute, f32 stats.
// Round 6: f16 residual stream (h32 eliminated), FFN2 128^2 split-K x4 with
//          f16 partials, O-proj 64x128 split-K x2 with f16 partials.
// ---------------------------------------------------------------------------

typedef _Float16 f16_t;
typedef _Float16 f16x8 __attribute__((ext_vector_type(8)));
typedef _Float16 f16x4 __attribute__((ext_vector_type(4)));
typedef _Float16 f16x2 __attribute__((ext_vector_type(2)));
typedef float    f32x4 __attribute__((ext_vector_type(4)));

#define LSTR 3145728LL  // per-layer transposed-weight stride (f16 elems)

__device__ __forceinline__ void gl_lds16(const f16_t* g, f16_t* l) {
    __builtin_amdgcn_global_load_lds(
        (const __attribute__((address_space(1))) unsigned int*)g,
        (__attribute__((address_space(3))) unsigned int*)l, 16, 0, 0);
}

// ---------------- pipelined batched GEMM: C = A[M,K] * (Bt[N,K])^T + bias ---
// A, Bt f16 row-major. blockIdx.z -> zh=z/zmod, zl=z%zmod; per-operand strides.
// Split-K via zmod=1: sAhi/sBhi = K-slice offset, sChi = C-slice stride.
// LDS: linear dest (global_load_lds), XOR-swizzled k-chunk on BOTH the global
// source and the LDS read offset (rule #21).
template<int BM, int BN, int WR, int WC, int OUTF16, int RELU>
__global__ void __launch_bounds__(256)
gemm_kernel(const f16_t* __restrict__ A, const f16_t* __restrict__ B,
            const float* __restrict__ bias, void* __restrict__ Cout,
            int M, int N, int K, int lda, int ldb, int ldc, int zmod,
            long long sAhi, long long sAlo, long long sBhi, long long sBlo,
            long long sChi, long long sClo)
{
    constexpr int BK  = 32;
    constexpr int WMT = BM / WR;
    constexpr int WNT = BN / WC;
    constexpr int MR  = WMT / 16;
    constexpr int NR  = WNT / 16;
    constexpr int IA  = BM / 64;        // global_load_lds issues per thread (A)
    constexpr int IB  = BN / 64;
    __shared__ __align__(16) f16_t As[2][BM][BK];
    __shared__ __align__(16) f16_t Bs[2][BN][BK];

    const int tid  = threadIdx.x;
    const int wid  = tid >> 6, lane = tid & 63;
    const int wr   = wid / WC, wc = wid % WC;
    const int z    = blockIdx.z;
    const int zh   = z / zmod, zl = z % zmod;
    const f16_t* Ab = A + (long long)zh * sAhi + (long long)zl * sAlo;
    const f16_t* Bb = B + (long long)zh * sBhi + (long long)zl * sBlo;
    const int m0 = blockIdx.x * BM;
    const int n0 = blockIdx.y * BN;

    f32x4 acc[MR][NR] = {};

    // ---- staging addresses: chunk c = i*256+tid; row=c>>2, kchunk=(c&3)^swz
    const f16_t* srcA[IA]; const f16_t* srcB[IB];
#pragma unroll
    for (int i = 0; i < IA; ++i) {
        const int c = i * 256 + tid, row = c >> 2;
        const int kch = (c & 3) ^ ((row >> 1) & 3);
        srcA[i] = Ab + (long long)(m0 + row) * lda + kch * 8;
    }
#pragma unroll
    for (int i = 0; i < IB; ++i) {
        const int c = i * 256 + tid, row = c >> 2;
        const int kch = (c & 3) ^ ((row >> 1) & 3);
        srcB[i] = Bb + (long long)(n0 + row) * ldb + kch * 8;
    }
    auto stage = [&](int bf_, int t) {
        const int k0 = t * BK;
#pragma unroll
        for (int i = 0; i < IA; ++i)
            gl_lds16(srcA[i] + k0, &As[bf_][0][0] + (i * 256 + wid * 64) * 8);
#pragma unroll
        for (int i = 0; i < IB; ++i)
            gl_lds16(srcB[i] + k0, &Bs[bf_][0][0] + (i * 256 + wid * 64) * 8);
    };

    // ---- fragment read offsets (bytes), swizzled to match staged layout
    const int l15 = lane & 15;
    const int kc  = (lane >> 4) * 8;    // 8 contiguous k per lane
    int aoff[MR], boff[NR];
#pragma unroll
    for (int m = 0; m < MR; ++m) {
        const int row = wr * WMT + m * 16 + l15;
        aoff[m] = ((row * BK + kc) * 2) ^ (((row >> 1) & 3) << 4);
    }
#pragma unroll
    for (int n = 0; n < NR; ++n) {
        const int row = wc * WNT + n * 16 + l15;
        boff[n] = ((row * BK + kc) * 2) ^ (((row >> 1) & 3) << 4);
    }

    const int NT = K / BK;
    stage(0, 0);
    __syncthreads();                    // drains vmcnt before barrier

    int buf = 0;
    for (int t = 0; t < NT; ++t) {
        if (t + 1 < NT) stage(buf ^ 1, t + 1);   // loads fly during MFMA
        const char* Al = (const char*)&As[buf][0][0];
        const char* Bl = (const char*)&Bs[buf][0][0];
        f16x8 af[MR], bfr[NR];
#pragma unroll
        for (int m = 0; m < MR; ++m) af[m]  = *(const f16x8*)(Al + aoff[m]);
#pragma unroll
        for (int n = 0; n < NR; ++n) bfr[n] = *(const f16x8*)(Bl + boff[n]);
#pragma unroll
        for (int m = 0; m < MR; ++m)
#pragma unroll
            for (int n = 0; n < NR; ++n)
                acc[m][n] = __builtin_amdgcn_mfma_f32_16x16x32_f16(af[m], bfr[n], acc[m][n], 0, 0, 0);
        __syncthreads();                // drains vmcnt+lgkmcnt, swap safe
        buf ^= 1;
    }

    const long long cOff = (long long)zh * sChi + (long long)zl * sClo;
    const int rbase = (lane >> 4) * 4;  // C/D: row=(lane>>4)*4+r, col=lane&15
#pragma unroll
    for (int m = 0; m < MR; ++m) {
        const int row = m0 + wr * WMT + m * 16 + rbase;
#pragma unroll
        for (int n = 0; n < NR; ++n) {
            const int col = n0 + wc * WNT + n * 16 + l15;
            const float bb = bias ? bias[col] : 0.0f;
#pragma unroll
            for (int r = 0; r < 4; ++r) {
                float v = acc[m][n][r] + bb;
                if (RELU) v = fmaxf(v, 0.0f);
                const long long idx = cOff + (long long)(row + r) * ldc + col;
                if (OUTF16) ((f16_t*)Cout)[idx] = (f16_t)v;
                else        ((float*)Cout)[idx] = v;
            }
        }
    }
}

// ------- flash attention per (b,h, 64-q tile): softmax(Q K^T) V -> ao -------
__global__ void __launch_bounds__(256)
attn_flash_kernel(const f16_t* __restrict__ qkv, const f16_t* __restrict__ Vt,
                  f16_t* __restrict__ ao)
{
    __shared__ __align__(16) f16_t Ks[512 * 64];   // 64KB
    __shared__ __align__(16) f16_t Qs[64 * 64];    //  8KB
    __shared__ __align__(16) f16_t Ps[4][16 * 64]; //  8KB (per-wave private)
    const int tid = threadIdx.x, wid = tid >> 6, lane = tid & 63;
    const int l15 = lane & 15, g = lane >> 4;
    const int z = blockIdx.y, b = z >> 3, hh = z & 7;
    const int q0 = blockIdx.x * 64;
    const f16_t* Kbase = qkv + (long long)b * 512 * 1536 + 512 + hh * 64;
    const f16_t* Qbase = qkv + (long long)(b * 512 + q0) * 1536 + hh * 64;
    const f16_t* Vbase = Vt + (long long)z * 32768;

    // stage K[512][64] and Q[64][64]; linear LDS dest, inverse-swizzled source
#pragma unroll
    for (int i = 0; i < 16; ++i) {
        const int c = i * 256 + tid, t = c >> 3, j = c & 7;
        gl_lds16(Kbase + (long long)t * 1536 + ((j ^ (t & 7)) << 3), Ks + c * 8);
    }
#pragma unroll
    for (int i = 0; i < 2; ++i) {
        const int c = i * 256 + tid, t = c >> 3, j = c & 7;
        gl_lds16(Qbase + (long long)t * 1536 + ((j ^ (t & 7)) << 3), Qs + c * 8);
    }
    __syncthreads();

    // hoisted Q B-frags: this wave's q rows = wid*16 + l15
    const int q = wid * 16 + l15;
    f16x8 qf[2];
#pragma unroll
    for (int k = 0; k < 2; ++k)
        qf[k] = *(const f16x8*)(Qs + q * 64 + (((k * 4 + g) ^ (l15 & 7)) << 3));

    f32x4 ov[4] = {};                   // O rows q=g*4+r, cols dv=n*16+l15
    float m_run = -1e30f, l_run = 0.0f;
    f16_t* Pw = &Ps[wid][0];

    for (int ck = 0; ck < 8; ++ck) {
        const int kc0 = ck * 64;
        f16x8 vf[4][2];
#pragma unroll
        for (int n = 0; n < 4; ++n)
#pragma unroll
            for (int k = 0; k < 2; ++k)
                vf[n][k] = *(const f16x8*)(Vbase + (n * 16 + l15) * 512 + kc0 + k * 32 + g * 8);
        // S^T = K_chunk . Q^T : rows=keys, cols=q
        f32x4 s[4] = {};
#pragma unroll
        for (int k = 0; k < 2; ++k)
#pragma unroll
            for (int m = 0; m < 4; ++m) {
                const int key = kc0 + m * 16 + l15;
                const f16x8 a = *(const f16x8*)(Ks + key * 64 + (((k * 4 + g) ^ (key & 7)) << 3));
                s[m] = __builtin_amdgcn_mfma_f32_16x16x32_f16(a, qf[k], s[m], 0, 0, 0);
            }
        // online softmax over keys for q = l15
        float cmax = -1e30f;
#pragma unroll
        for (int m = 0; m < 4; ++m)
#pragma unroll
            for (int r = 0; r < 4; ++r) cmax = fmaxf(cmax, s[m][r]);
        cmax = fmaxf(cmax, __shfl_xor(cmax, 16, 64));
        cmax = fmaxf(cmax, __shfl_xor(cmax, 32, 64));
        const float mnew = fmaxf(m_run, cmax);
        const float corr = __expf(m_run - mnew);
        float csum = 0.0f;
#pragma unroll
        for (int m = 0; m < 4; ++m) {
            f16x4 p4;
#pragma unroll
            for (int r = 0; r < 4; ++r) {
                const float pe = __expf(s[m][r] - mnew);
                csum += pe;
                p4[r] = (f16_t)pe;
            }
            *(f16x4*)(Pw + l15 * 64 + ((((m * 2 + (g >> 1)) ^ (l15 & 7))) << 3) + ((g & 1) << 2)) = p4;
        }
        csum += __shfl_xor(csum, 16, 64);
        csum += __shfl_xor(csum, 32, 64);
        l_run = l_run * corr + csum;
        m_run = mnew;
        float cr[4];
#pragma unroll
        for (int r = 0; r < 4; ++r) cr[r] = __shfl(corr, g * 4 + r, 64);
#pragma unroll
        for (int n = 0; n < 4; ++n)
#pragma unroll
            for (int r = 0; r < 4; ++r) ov[n][r] *= cr[r];
#pragma unroll
        for (int k = 0; k < 2; ++k) {
            const f16x8 pf = *(const f16x8*)(Pw + l15 * 64 + (((k * 4 + g) ^ (l15 & 7)) << 3));
#pragma unroll
            for (int n = 0; n < 4; ++n)
                ov[n] = __builtin_amdgcn_mfma_f32_16x16x32_f16(pf, vf[n][k], ov[n], 0, 0, 0);
        }
    }

    const float inv = 1.0f / l_run;
    float ir[4];
#pragma unroll
    for (int r = 0; r < 4; ++r) ir[r] = __shfl(inv, g * 4 + r, 64);
#pragma unroll
    for (int n = 0; n < 4; ++n)
#pragma unroll
        for (int r = 0; r < 4; ++r) {
            const long long row = b * 512 + q0 + wid * 16 + g * 4 + r;
            ao[row * 512 + hh * 64 + n * 16 + l15] = (f16_t)(ov[n][r] * ir[r]);
        }
}

// ---------------- weight convert+transpose f32 -> f16, [K,N] -> [N,K] -------
__global__ void wconv_kernel(const float* __restrict__ Wq, const float* __restrict__ Wk,
                             const float* __restrict__ Wv, const float* __restrict__ Wo,
                             const float* __restrict__ W1, const float* __restrict__ W2,
                             f16_t* __restrict__ wT)
{
    __shared__ float tile[32][33];
    const int t     = blockIdx.x;       // 18432 tiles = 6 layers * 3072
    const int layer = t / 3072;
    const int r     = t % 3072;
    const float* src; f16_t* dst; int R, C, tt;
    if (r < 1024) {                     // Wq,Wk,Wv,Wo: [512,512]
        const int mat = r >> 8; tt = r & 255; R = 512; C = 512;
        const float* s4 = (mat == 0) ? Wq : (mat == 1) ? Wk : (mat == 2) ? Wv : Wo;
        src = s4 + (long long)layer * 262144;
        dst = wT + (long long)layer * LSTR + (long long)mat * 262144;
    } else if (r < 2048) {              // W1: [512,2048] -> [2048,512]
        tt = r - 1024; R = 512; C = 2048;
        src = W1 + (long long)layer * 1048576;
        dst = wT + (long long)layer * LSTR + 1048576;
    } else {                            // W2: [2048,512] -> [512,2048]
        tt = r - 2048; R = 2048; C = 512;
        src = W2 + (long long)layer * 1048576;
        dst = wT + (long long)layer * LSTR + 2097152;
    }
    const int tC = C >> 5;
    const int tr = tt / tC, tc = tt % tC;
    const int r0 = tr * 32, c0 = tc * 32;
    const int tx = threadIdx.x, ty = threadIdx.y;
#pragma unroll
    for (int i = 0; i < 4; ++i)
        tile[ty + 8 * i][tx] = src[(long long)(r0 + ty + 8 * i) * C + c0 + tx];
    __syncthreads();
#pragma unroll
    for (int i = 0; i < 4; ++i)
        dst[(long long)(c0 + ty + 8 * i) * R + r0 + tx] = (f16_t)tile[tx][ty + 8 * i];
}

// ---------------- concat per-layer [bq|bk|bv] -> [6][1536] ------------------
__global__ void biascat_kernel(const float* __restrict__ bq, const float* __restrict__ bk,
                               const float* __restrict__ bv, float* __restrict__ qkvb)
{
    const int i = blockIdx.x * 256 + threadIdx.x;
    if (i >= 9216) return;
    const int l = i / 1536, c = i % 1536;
    float v;
    if (c < 512)       v = bq[l * 512 + c];
    else if (c < 1024) v = bk[l * 512 + c - 512];
    else               v = bv[l * 512 + c - 1024];
    qkvb[i] = v;
}

// ---------------- embedding gather + sinusoidal PE (f16 stream) -------------
__global__ void embed_kernel(const int* __restrict__ xt, const float* __restrict__ emb,
                             f16_t* __restrict__ hb)
{
    const int row = blockIdx.x;         // b*512 + t
    const int t   = row & 511;
    const int tok = xt[row];
    const int tid = threadIdx.x;
#pragma unroll
    for (int s = 0; s < 2; ++s) {
        const int d = tid + s * 256;
        const int i = d >> 1;
        const float inv = expf((float)(2 * i) * (-9.210340371976184f / 512.0f));
        const float ang = (float)t * inv;
        const float pe  = (d & 1) ? cosf(ang) : sinf(ang);
        hb[(long long)row * 512 + d] = (f16_t)(emb[(long long)tok * 512 + d] + pe);
    }
}

// ---- hb = LN( sum_{s<ns} X[s] + bias + hb ), all-f16 I/O, f32 stats --------
__global__ void add_ln_kernel(const f16_t* __restrict__ X, int ns, long long sstr,
                              const float* __restrict__ bias,
                              const float* __restrict__ g, const float* __restrict__ b,
                              f16_t* __restrict__ Hf)
{
    __shared__ float red[4], red2[4];
    const long long row = blockIdx.x;
    f16_t* h = Hf + row * 512;
    const int tid = threadIdx.x;
    const int c0 = 2 * tid;
    const f16x2 hv = *(const f16x2*)&h[c0];
    float s0 = (float)hv[0] + bias[c0];
    float s1 = (float)hv[1] + bias[c0 + 1];
    for (int s = 0; s < ns; ++s) {
        const f16x2 xv = *(const f16x2*)&X[s * sstr + row * 512 + c0];
        s0 += (float)xv[0];
        s1 += (float)xv[1];
    }
    float sum = s0 + s1, sq = s0 * s0 + s1 * s1;
#pragma unroll
    for (int o = 32; o > 0; o >>= 1) { sum += __shfl_down(sum, o, 64); sq += __shfl_down(sq, o, 64); }
    if ((tid & 63) == 0) { red[tid >> 6] = sum; red2[tid >> 6] = sq; }
    __syncthreads();
    sum = red[0] + red[1] + red[2] + red[3];
    sq  = red2[0] + red2[1] + red2[2] + red2[3];
    const float mu = sum * (1.0f / 512.0f);
    float var = sq * (1.0f / 512.0f) - mu * mu;
    var = fmaxf(var, 0.0f);
    const float rs = rsqrtf(var + 1e-5f);
    f16x2 o2;
    o2[0] = (f16_t)(g[c0]     * (s0 - mu) * rs + b[c0]);
    o2[1] = (f16_t)(g[c0 + 1] * (s1 - mu) * rs + b[c0 + 1]);
    *(f16x2*)&h[c0] = o2;
}

// ---------------- V_head [T,64] -> Vt [64,T] per (b,h) ----------------------
__global__ void vtrans_kernel(const f16_t* __restrict__ qkv, f16_t* __restrict__ Vt)
{
    __shared__ f16_t tl[32][34];
    const int z  = blockIdx.y;          // b*8 + h
    const int b  = z >> 3, hh = z & 7;
    const int tile = blockIdx.x;        // 0..31: 16 t-tiles x 2 c-tiles
    const int tr = tile >> 1, tc = tile & 1;
    const int t0 = tr * 32, c0 = tc * 32;
    const int tx = threadIdx.x, ty = threadIdx.y;
#pragma unroll
    for (int i = 0; i < 4; ++i)
        tl[ty + 8 * i][tx] = qkv[(long long)(b * 512 + t0 + ty + 8 * i) * 1536 + 1024 + hh * 64 + c0 + tx];
    __syncthreads();
#pragma unroll
    for (int i = 0; i < 4; ++i)
        Vt[((long long)z * 64 + c0 + ty + 8 * i) * 512 + t0 + tx] = tl[tx][ty + 8 * i];
}

// ---------------- classifier head: split reduction (hb f16) -----------------
__global__ void head_partial_kernel(const f16_t* __restrict__ hb, const float* __restrict__ Wout,
                                    float* __restrict__ partials)
{
    const int blk = blockIdx.x;         // 8 b * 64 chunks
    const int b = blk >> 6, chunk = blk & 63;
    const int tid = threadIdx.x;
    const f16_t* hp = hb + (long long)b * 262144 + (long long)chunk * 4096;
    float a0 = 0, a1 = 0, a2 = 0, a3 = 0, a4 = 0;
    for (int it = 0; it < 16; ++it) {
        const int idx = it * 256 + tid;
        const float hv = (float)hp[idx];
        const float* w = Wout + ((long long)chunk * 4096 + idx) * 5;
        a0 += hv * w[0]; a1 += hv * w[1]; a2 += hv * w[2]; a3 += hv * w[3]; a4 += hv * w[4];
    }
#pragma unroll
    for (int o = 32; o > 0; o >>= 1) {
        a0 += __shfl_down(a0, o, 64); a1 += __shfl_down(a1, o, 64); a2 += __shfl_down(a2, o, 64);
        a3 += __shfl_down(a3, o, 64); a4 += __shfl_down(a4, o, 64);
    }
    __shared__ float sm[4][5];
    const int lane = tid & 63, w = tid >> 6;
    if (lane == 0) { sm[w][0] = a0; sm[w][1] = a1; sm[w][2] = a2; sm[w][3] = a3; sm[w][4] = a4; }
    __syncthreads();
    if (tid < 5)
        partials[(long long)blk * 5 + tid] = sm[0][tid] + sm[1][tid] + sm[2][tid] + sm[3][tid];
}

__global__ void head_final_kernel(const float* __restrict__ partials, const float* __restrict__ bout,
                                  float* __restrict__ out)
{
    const int tid = threadIdx.x;
    if (tid >= 40) return;
    const int b = tid / 5, c = tid % 5;
    float s = bout[c];
    const float* p = partials + (long long)b * 64 * 5 + c;
    for (int ck = 0; ck < 64; ++ck) s += p[ck * 5];
    out[tid] = s;   // reference output dtype is float32
}

// ---------------------------------------------------------------------------
extern "C" void kernel_launch(void* const* d_in, const int* in_sizes, int n_in,
                              void* d_out, int out_size, void* d_ws, size_t ws_size,
                              hipStream_t stream)
{
    (void)in_sizes; (void)n_in; (void)out_size; (void)ws_size;
    const int*   x_tok = (const int*)  d_in[0];
    const float* emb   = (const float*)d_in[2];
    const float* Wq    = (const float*)d_in[3];
    const float* bq    = (const float*)d_in[4];
    const float* Wk    = (const float*)d_in[5];
    const float* bk    = (const float*)d_in[6];
    const float* Wv    = (const float*)d_in[7];
    const float* bv    = (const float*)d_in[8];
    const float* Wo    = (const float*)d_in[9];
    const float* bo    = (const float*)d_in[10];
    const float* gma   = (const float*)d_in[11];
    const float* bta   = (const float*)d_in[12];
    const float* W1    = (const float*)d_in[13];
    const float* b1    = (const float*)d_in[14];
    const float* W2    = (const float*)d_in[15];
    const float* b2    = (const float*)d_in[16];
    const float* Wout  = (const float*)d_in[17];
    const float* bout  = (const float*)d_in[18];

    char* ws = (char*)d_ws;
    size_t off = 0;
    auto take = [&](size_t bytes) { char* p = ws + off; off += (bytes + 255) & ~(size_t)255; return p; };
    f16_t* wT    = (f16_t*)take(18874368ULL * 2);  // transposed f16 weights
    f16_t* hb    = (f16_t*)take(2097152ULL * 2);   // residual stream (f16)
    f16_t* qkv   = (f16_t*)take(6291456ULL * 2);   // [4096][1536]
    f16_t* Vt    = (f16_t*)take(2097152ULL * 2);   // [64][64][512]
    f16_t* ao    = (f16_t*)take(2097152ULL * 2);   // attn out [4096][512]
    f16_t* f1    = (f16_t*)take(8388608ULL * 2);   // ffn hidden [4096][2048]
    f16_t* t16   = (f16_t*)take(4ULL * 2097152ULL * 2); // split-K f16 partials
    float* qkvb  = (float*)take(9216ULL * 4);
    float* parts = (float*)take(2560ULL * 4);

    wconv_kernel <<<dim3(18432), dim3(32, 8), 0, stream>>>(Wq, Wk, Wv, Wo, W1, W2, wT);
    biascat_kernel<<<dim3(36), 256, 0, stream>>>(bq, bk, bv, qkvb);
    embed_kernel <<<dim3(4096), 256, 0, stream>>>(x_tok, emb, hb);

    for (int l = 0; l < 6; ++l) {
        const f16_t* wl = wT + (long long)l * LSTR;
        // QKV: [4096,512] @ [512,1536] -> qkv f16 (768 blocks, 3/CU)
        gemm_kernel<64,128,2,2,1,0><<<dim3(64,12,1),256,0,stream>>>(hb, wl, qkvb + l*1536, qkv,
            4096,1536,512, 512,512,1536, 1, 0,0,0,0,0,0);
        vtrans_kernel<<<dim3(32,64), dim3(32,8), 0, stream>>>(qkv, Vt);
        // flash attention: softmax(QK^T)V -> ao, S never materialized
        attn_flash_kernel<<<dim3(8,64),256,0,stream>>>(qkv, Vt, ao);
        // O proj: 64x128 split-K x2 (512 blocks, 2/CU) -> t16 slices
        gemm_kernel<64,128,2,2,1,0><<<dim3(64,4,2),256,0,stream>>>(ao, wl + 786432, nullptr, t16,
            4096,512,256, 512,512,512, 1, 256LL,0LL, 256LL,0LL, 2097152LL,0LL);
        add_ln_kernel<<<dim3(4096),256,0,stream>>>(t16, 2, 2097152LL, bo + l*512,
            gma + l*512, bta + l*512, hb);
        // FFN1 + relu -> f1 f16, 128x128 tiles (512 blocks, 2/CU)
        gemm_kernel<128,128,2,2,1,1><<<dim3(32,16,1),256,0,stream>>>(hb, wl + 1048576, b1 + l*2048, f1,
            4096,2048,512, 512,512,2048, 1, 0,0,0,0,0,0);
        // FFN2: 128x128 split-K x4 (512 blocks, 2/CU) -> t16 slices
        gemm_kernel<128,128,2,2,1,0><<<dim3(32,4,4),256,0,stream>>>(f1, wl + 2097152, nullptr, t16,
            4096,512,512, 2048,2048,512, 1, 512LL,0LL, 512LL,0LL, 2097152LL,0LL);
        add_ln_kernel<<<dim3(4096),256,0,stream>>>(t16, 4, 2097152LL, b2 + l*512,
            gma + l*512, bta + l*512, hb);
    }

    head_partial_kernel<<<dim3(512),256,0,stream>>>(hb, Wout, parts);
    head_final_kernel  <<<dim3(1),64,0,stream>>>(parts, bout, (float*)d_out);
}

// Round 7
// 588.661 us; speedup vs baseline: 2.1243x; 1.0608x over previous
//
#include <hip/hip_runtime.h>
#include <hip/hip_bf16.h>

// ---------------------------------------------------------------------------
// 6-layer transformer forward, MI355X. f16 MFMA compute, f32 stats.
// Round 7: V-transpose fused into QKV epilogue (vtrans killed), BK=64
//          half-barrier GEMM (64x128 tiles, 48KB LDS, 3 blocks/CU),
//          barrier-free wave-per-row add_ln.
// ---------------------------------------------------------------------------

typedef _Float16 f16_t;
typedef _Float16 f16x8 __attribute__((ext_vector_type(8)));
typedef _Float16 f16x4 __attribute__((ext_vector_type(4)));
typedef _Float16 f16x2 __attribute__((ext_vector_type(2)));
typedef float    f32x4 __attribute__((ext_vector_type(4)));

#define LSTR 3145728LL  // per-layer transposed-weight stride (f16 elems)

__device__ __forceinline__ void gl_lds16(const f16_t* g, f16_t* l) {
    __builtin_amdgcn_global_load_lds(
        (const __attribute__((address_space(1))) unsigned int*)g,
        (__attribute__((address_space(3))) unsigned int*)l, 16, 0, 0);
}

// ---------------- pipelined batched GEMM: C = A[M,K] * (Bt[N,K])^T + bias ---
// A, Bt f16 row-major. blockIdx.z -> zh=z/zmod, zl=z%zmod; per-operand strides.
// Split-K via zmod=1: sAhi/sBhi = K-slice offset, sChi = C-slice stride.
// LDS: linear dest (global_load_lds), XOR-swizzled 16B k-chunk on BOTH the
// global source and the LDS read offset (rule #21). BK=64: swz=row&7 (rows
// alias every row at 128B stride); BK=32: swz=(row>>1)&3.
// VOUT=1 (QKV): cols>=1024 are V heads -> written transposed to vt
// ([b*8+h][64][512]) as f16x4 (4 consecutive t per fragment); qkv gets Q,K.
template<int BM, int BN, int BK, int WR, int WC, int OUTF16, int RELU, int VOUT>
__global__ void __launch_bounds__(256)
gemm_kernel(const f16_t* __restrict__ A, const f16_t* __restrict__ B,
            const float* __restrict__ bias, void* __restrict__ Cout,
            f16_t* __restrict__ vt,
            int M, int N, int K, int lda, int ldb, int ldc, int zmod,
            long long sAhi, long long sAlo, long long sBhi, long long sBlo,
            long long sChi, long long sClo)
{
    constexpr int WMT = BM / WR;
    constexpr int WNT = BN / WC;
    constexpr int MR  = WMT / 16;
    constexpr int NR  = WNT / 16;
    constexpr int KK  = BK / 32;        // 16x16x32 MFMA k-substeps per K-step
    constexpr int CPR = BK / 8;         // 16B chunks per LDS row
    constexpr int RS  = (BK == 32) ? 1 : 0;
    constexpr int IA  = BM * BK / 2048; // global_load_lds issues per thread
    constexpr int IB  = BN * BK / 2048;
    __shared__ __align__(16) f16_t As[2][BM][BK];
    __shared__ __align__(16) f16_t Bs[2][BN][BK];

    const int tid  = threadIdx.x;
    const int wid  = tid >> 6, lane = tid & 63;
    const int wr   = wid / WC, wc = wid % WC;
    const int z    = blockIdx.z;
    const int zh   = z / zmod, zl = z % zmod;
    const f16_t* Ab = A + (long long)zh * sAhi + (long long)zl * sAlo;
    const f16_t* Bb = B + (long long)zh * sBhi + (long long)zl * sBlo;
    const int m0 = blockIdx.x * BM;
    const int n0 = blockIdx.y * BN;

    f32x4 acc[MR][NR] = {};

    // ---- staging addresses: chunk c=i*256+tid; row=c/CPR, j=c%CPR, j^=swz
    const f16_t* srcA[IA]; const f16_t* srcB[IB];
#pragma unroll
    for (int i = 0; i < IA; ++i) {
        const int c = i * 256 + tid, row = c / CPR;
        const int kch = (c % CPR) ^ ((row >> RS) & (CPR - 1));
        srcA[i] = Ab + (long long)(m0 + row) * lda + kch * 8;
    }
#pragma unroll
    for (int i = 0; i < IB; ++i) {
        const int c = i * 256 + tid, row = c / CPR;
        const int kch = (c % CPR) ^ ((row >> RS) & (CPR - 1));
        srcB[i] = Bb + (long long)(n0 + row) * ldb + kch * 8;
    }
    auto stage = [&](int bf_, int t) {
        const int k0 = t * BK;
#pragma unroll
        for (int i = 0; i < IA; ++i)
            gl_lds16(srcA[i] + k0, &As[bf_][0][0] + (i * 256 + wid * 64) * 8);
#pragma unroll
        for (int i = 0; i < IB; ++i)
            gl_lds16(srcB[i] + k0, &Bs[bf_][0][0] + (i * 256 + wid * 64) * 8);
    };

    // ---- fragment read offsets (bytes), swizzled to match staged layout
    const int l15 = lane & 15;
    const int g   = lane >> 4;
    int aoff[MR][KK], boff[NR][KK];
#pragma unroll
    for (int m = 0; m < MR; ++m) {
        const int row = wr * WMT + m * 16 + l15;
        const int swz = ((row >> RS) & (CPR - 1)) << 4;
#pragma unroll
        for (int kk = 0; kk < KK; ++kk)
            aoff[m][kk] = ((row * BK + kk * 32 + g * 8) * 2) ^ swz;
    }
#pragma unroll
    for (int n = 0; n < NR; ++n) {
        const int row = wc * WNT + n * 16 + l15;
        const int swz = ((row >> RS) & (CPR - 1)) << 4;
#pragma unroll
        for (int kk = 0; kk < KK; ++kk)
            boff[n][kk] = ((row * BK + kk * 32 + g * 8) * 2) ^ swz;
    }

    const int NT = K / BK;
    stage(0, 0);
    __syncthreads();                    // drains vmcnt before barrier

    int buf = 0;
    for (int t = 0; t < NT; ++t) {
        if (t + 1 < NT) stage(buf ^ 1, t + 1);   // loads fly during MFMA
        const char* Al = (const char*)&As[buf][0][0];
        const char* Bl = (const char*)&Bs[buf][0][0];
        f16x8 af[MR][KK], bfr[NR][KK];
#pragma unroll
        for (int m = 0; m < MR; ++m)
#pragma unroll
            for (int kk = 0; kk < KK; ++kk) af[m][kk] = *(const f16x8*)(Al + aoff[m][kk]);
#pragma unroll
        for (int n = 0; n < NR; ++n)
#pragma unroll
            for (int kk = 0; kk < KK; ++kk) bfr[n][kk] = *(const f16x8*)(Bl + boff[n][kk]);
#pragma unroll
        for (int kk = 0; kk < KK; ++kk)
#pragma unroll
            for (int m = 0; m < MR; ++m)
#pragma unroll
                for (int n = 0; n < NR; ++n)
                    acc[m][n] = __builtin_amdgcn_mfma_f32_16x16x32_f16(af[m][kk], bfr[n][kk], acc[m][n], 0, 0, 0);
        __syncthreads();                // drains vmcnt+lgkmcnt, swap safe
        buf ^= 1;
    }

    const long long cOff = (long long)zh * sChi + (long long)zl * sClo;
    const int rbase = (lane >> 4) * 4;  // C/D: row=(lane>>4)*4+r, col=lane&15
#pragma unroll
    for (int m = 0; m < MR; ++m) {
        const int row = m0 + wr * WMT + m * 16 + rbase;
#pragma unroll
        for (int n = 0; n < NR; ++n) {
            const int col = n0 + wc * WNT + n * 16 + l15;
            const float bb = bias ? bias[col] : 0.0f;
            if (VOUT && col >= 1024) {  // V head -> transposed f16x4 store
                const int hh = (col - 1024) >> 6, dv = (col - 1024) & 63;
                const int bb_ = row >> 9, t0 = row & 511;
                f16x4 v4;
#pragma unroll
                for (int r = 0; r < 4; ++r) v4[r] = (f16_t)(acc[m][n][r] + bb);
                *(f16x4*)&vt[((long long)((bb_ * 8 + hh) * 64 + dv)) * 512 + t0] = v4;
            } else {
#pragma unroll
                for (int r = 0; r < 4; ++r) {
                    float v = acc[m][n][r] + bb;
                    if (RELU) v = fmaxf(v, 0.0f);
                    const long long idx = cOff + (long long)(row + r) * ldc + col;
                    if (OUTF16) ((f16_t*)Cout)[idx] = (f16_t)v;
                    else        ((float*)Cout)[idx] = v;
                }
            }
        }
    }
}

// ------- flash attention per (b,h, 64-q tile): softmax(Q K^T) V -> ao -------
__global__ void __launch_bounds__(256)
attn_flash_kernel(const f16_t* __restrict__ qkv, const f16_t* __restrict__ Vt,
                  f16_t* __restrict__ ao)
{
    __shared__ __align__(16) f16_t Ks[512 * 64];   // 64KB
    __shared__ __align__(16) f16_t Qs[64 * 64];    //  8KB
    __shared__ __align__(16) f16_t Ps[4][16 * 64]; //  8KB (per-wave private)
    const int tid = threadIdx.x, wid = tid >> 6, lane = tid & 63;
    const int l15 = lane & 15, g = lane >> 4;
    const int z = blockIdx.y, b = z >> 3, hh = z & 7;
    const int q0 = blockIdx.x * 64;
    const f16_t* Kbase = qkv + (long long)b * 512 * 1536 + 512 + hh * 64;
    const f16_t* Qbase = qkv + (long long)(b * 512 + q0) * 1536 + hh * 64;
    const f16_t* Vbase = Vt + (long long)z * 32768;

    // stage K[512][64] and Q[64][64]; linear LDS dest, inverse-swizzled source
#pragma unroll
    for (int i = 0; i < 16; ++i) {
        const int c = i * 256 + tid, t = c >> 3, j = c & 7;
        gl_lds16(Kbase + (long long)t * 1536 + ((j ^ (t & 7)) << 3), Ks + c * 8);
    }
#pragma unroll
    for (int i = 0; i < 2; ++i) {
        const int c = i * 256 + tid, t = c >> 3, j = c & 7;
        gl_lds16(Qbase + (long long)t * 1536 + ((j ^ (t & 7)) << 3), Qs + c * 8);
    }
    __syncthreads();

    // hoisted Q B-frags: this wave's q rows = wid*16 + l15
    const int q = wid * 16 + l15;
    f16x8 qf[2];
#pragma unroll
    for (int k = 0; k < 2; ++k)
        qf[k] = *(const f16x8*)(Qs + q * 64 + (((k * 4 + g) ^ (l15 & 7)) << 3));

    f32x4 ov[4] = {};                   // O rows q=g*4+r, cols dv=n*16+l15
    float m_run = -1e30f, l_run = 0.0f;
    f16_t* Pw = &Ps[wid][0];

    for (int ck = 0; ck < 8; ++ck) {
        const int kc0 = ck * 64;
        f16x8 vf[4][2];
#pragma unroll
        for (int n = 0; n < 4; ++n)
#pragma unroll
            for (int k = 0; k < 2; ++k)
                vf[n][k] = *(const f16x8*)(Vbase + (n * 16 + l15) * 512 + kc0 + k * 32 + g * 8);
        // S^T = K_chunk . Q^T : rows=keys, cols=q
        f32x4 s[4] = {};
#pragma unroll
        for (int k = 0; k < 2; ++k)
#pragma unroll
            for (int m = 0; m < 4; ++m) {
                const int key = kc0 + m * 16 + l15;
                const f16x8 a = *(const f16x8*)(Ks + key * 64 + (((k * 4 + g) ^ (key & 7)) << 3));
                s[m] = __builtin_amdgcn_mfma_f32_16x16x32_f16(a, qf[k], s[m], 0, 0, 0);
            }
        // online softmax over keys for q = l15
        float cmax = -1e30f;
#pragma unroll
        for (int m = 0; m < 4; ++m)
#pragma unroll
            for (int r = 0; r < 4; ++r) cmax = fmaxf(cmax, s[m][r]);
        cmax = fmaxf(cmax, __shfl_xor(cmax, 16, 64));
        cmax = fmaxf(cmax, __shfl_xor(cmax, 32, 64));
        const float mnew = fmaxf(m_run, cmax);
        const float corr = __expf(m_run - mnew);
        float csum = 0.0f;
#pragma unroll
        for (int m = 0; m < 4; ++m) {
            f16x4 p4;
#pragma unroll
            for (int r = 0; r < 4; ++r) {
                const float pe = __expf(s[m][r] - mnew);
                csum += pe;
                p4[r] = (f16_t)pe;
            }
            *(f16x4*)(Pw + l15 * 64 + ((((m * 2 + (g >> 1)) ^ (l15 & 7))) << 3) + ((g & 1) << 2)) = p4;
        }
        csum += __shfl_xor(csum, 16, 64);
        csum += __shfl_xor(csum, 32, 64);
        l_run = l_run * corr + csum;
        m_run = mnew;
        float cr[4];
#pragma unroll
        for (int r = 0; r < 4; ++r) cr[r] = __shfl(corr, g * 4 + r, 64);
#pragma unroll
        for (int n = 0; n < 4; ++n)
#pragma unroll
            for (int r = 0; r < 4; ++r) ov[n][r] *= cr[r];
#pragma unroll
        for (int k = 0; k < 2; ++k) {
            const f16x8 pf = *(const f16x8*)(Pw + l15 * 64 + (((k * 4 + g) ^ (l15 & 7)) << 3));
#pragma unroll
            for (int n = 0; n < 4; ++n)
                ov[n] = __builtin_amdgcn_mfma_f32_16x16x32_f16(pf, vf[n][k], ov[n], 0, 0, 0);
        }
    }

    const float inv = 1.0f / l_run;
    float ir[4];
#pragma unroll
    for (int r = 0; r < 4; ++r) ir[r] = __shfl(inv, g * 4 + r, 64);
#pragma unroll
    for (int n = 0; n < 4; ++n)
#pragma unroll
        for (int r = 0; r < 4; ++r) {
            const long long row = b * 512 + q0 + wid * 16 + g * 4 + r;
            ao[row * 512 + hh * 64 + n * 16 + l15] = (f16_t)(ov[n][r] * ir[r]);
        }
}

// ---------------- weight convert+transpose f32 -> f16, [K,N] -> [N,K] -------
__global__ void wconv_kernel(const float* __restrict__ Wq, const float* __restrict__ Wk,
                             const float* __restrict__ Wv, const float* __restrict__ Wo,
                             const float* __restrict__ W1, const float* __restrict__ W2,
                             f16_t* __restrict__ wT)
{
    __shared__ float tile[32][33];
    const int t     = blockIdx.x;       // 18432 tiles = 6 layers * 3072
    const int layer = t / 3072;
    const int r     = t % 3072;
    const float* src; f16_t* dst; int R, C, tt;
    if (r < 1024) {                     // Wq,Wk,Wv,Wo: [512,512]
        const int mat = r >> 8; tt = r & 255; R = 512; C = 512;
        const float* s4 = (mat == 0) ? Wq : (mat == 1) ? Wk : (mat == 2) ? Wv : Wo;
        src = s4 + (long long)layer * 262144;
        dst = wT + (long long)layer * LSTR + (long long)mat * 262144;
    } else if (r < 2048) {              // W1: [512,2048] -> [2048,512]
        tt = r - 1024; R = 512; C = 2048;
        src = W1 + (long long)layer * 1048576;
        dst = wT + (long long)layer * LSTR + 1048576;
    } else {                            // W2: [2048,512] -> [512,2048]
        tt = r - 2048; R = 2048; C = 512;
        src = W2 + (long long)layer * 1048576;
        dst = wT + (long long)layer * LSTR + 2097152;
    }
    const int tC = C >> 5;
    const int tr = tt / tC, tc = tt % tC;
    const int r0 = tr * 32, c0 = tc * 32;
    const int tx = threadIdx.x, ty = threadIdx.y;
#pragma unroll
    for (int i = 0; i < 4; ++i)
        tile[ty + 8 * i][tx] = src[(long long)(r0 + ty + 8 * i) * C + c0 + tx];
    __syncthreads();
#pragma unroll
    for (int i = 0; i < 4; ++i)
        dst[(long long)(c0 + ty + 8 * i) * R + r0 + tx] = (f16_t)tile[tx][ty + 8 * i];
}

// ---------------- concat per-layer [bq|bk|bv] -> [6][1536] ------------------
__global__ void biascat_kernel(const float* __restrict__ bq, const float* __restrict__ bk,
                               const float* __restrict__ bv, float* __restrict__ qkvb)
{
    const int i = blockIdx.x * 256 + threadIdx.x;
    if (i >= 9216) return;
    const int l = i / 1536, c = i % 1536;
    float v;
    if (c < 512)       v = bq[l * 512 + c];
    else if (c < 1024) v = bk[l * 512 + c - 512];
    else               v = bv[l * 512 + c - 1024];
    qkvb[i] = v;
}

// ---------------- embedding gather + sinusoidal PE (f16 stream) -------------
__global__ void embed_kernel(const int* __restrict__ xt, const float* __restrict__ emb,
                             f16_t* __restrict__ hb)
{
    const int row = blockIdx.x;         // b*512 + t
    const int t   = row & 511;
    const int tok = xt[row];
    const int tid = threadIdx.x;
#pragma unroll
    for (int s = 0; s < 2; ++s) {
        const int d = tid + s * 256;
        const int i = d >> 1;
        const float inv = expf((float)(2 * i) * (-9.210340371976184f / 512.0f));
        const float ang = (float)t * inv;
        const float pe  = (d & 1) ? cosf(ang) : sinf(ang);
        hb[(long long)row * 512 + d] = (f16_t)(emb[(long long)tok * 512 + d] + pe);
    }
}

// ---- hb = LN( sum_{s<ns} X[s] + bias + hb ); wave-per-row, no barriers -----
__global__ void __launch_bounds__(256)
add_ln_kernel(const f16_t* __restrict__ X, int ns, long long sstr,
              const float* __restrict__ bias,
              const float* __restrict__ g, const float* __restrict__ b,
              f16_t* __restrict__ Hf)
{
    const int wid = threadIdx.x >> 6, lane = threadIdx.x & 63;
    const long long row = (long long)blockIdx.x * 4 + wid;
    f16_t* h = Hf + row * 512;
    const int c0 = lane * 8;
    const f16x8 hv = *(const f16x8*)&h[c0];
    float v[8];
#pragma unroll
    for (int e = 0; e < 8; ++e) v[e] = (float)hv[e] + bias[c0 + e];
    for (int s = 0; s < ns; ++s) {
        const f16x8 xv = *(const f16x8*)&X[s * sstr + row * 512 + c0];
#pragma unroll
        for (int e = 0; e < 8; ++e) v[e] += (float)xv[e];
    }
    float sum = 0.0f, sq = 0.0f;
#pragma unroll
    for (int e = 0; e < 8; ++e) { sum += v[e]; sq += v[e] * v[e]; }
#pragma unroll
    for (int o = 1; o < 64; o <<= 1) {
        sum += __shfl_xor(sum, o, 64);
        sq  += __shfl_xor(sq,  o, 64);
    }
    const float mu = sum * (1.0f / 512.0f);
    float var = sq * (1.0f / 512.0f) - mu * mu;
    var = fmaxf(var, 0.0f);
    const float rs = rsqrtf(var + 1e-5f);
    f16x8 o8;
#pragma unroll
    for (int e = 0; e < 8; ++e)
        o8[e] = (f16_t)(g[c0 + e] * (v[e] - mu) * rs + b[c0 + e]);
    *(f16x8*)&h[c0] = o8;
}

// ---------------- classifier head: split reduction (hb f16) -----------------
__global__ void head_partial_kernel(const f16_t* __restrict__ hb, const float* __restrict__ Wout,
                                    float* __restrict__ partials)
{
    const int blk = blockIdx.x;         // 8 b * 64 chunks
    const int b = blk >> 6, chunk = blk & 63;
    const int tid = threadIdx.x;
    const f16_t* hp = hb + (long long)b * 262144 + (long long)chunk * 4096;
    float a0 = 0, a1 = 0, a2 = 0, a3 = 0, a4 = 0;
    for (int it = 0; it < 16; ++it) {
        const int idx = it * 256 + tid;
        const float hv = (float)hp[idx];
        const float* w = Wout + ((long long)chunk * 4096 + idx) * 5;
        a0 += hv * w[0]; a1 += hv * w[1]; a2 += hv * w[2]; a3 += hv * w[3]; a4 += hv * w[4];
    }
#pragma unroll
    for (int o = 32; o > 0; o >>= 1) {
        a0 += __shfl_down(a0, o, 64); a1 += __shfl_down(a1, o, 64); a2 += __shfl_down(a2, o, 64);
        a3 += __shfl_down(a3, o, 64); a4 += __shfl_down(a4, o, 64);
    }
    __shared__ float sm[4][5];
    const int lane = tid & 63, w = tid >> 6;
    if (lane == 0) { sm[w][0] = a0; sm[w][1] = a1; sm[w][2] = a2; sm[w][3] = a3; sm[w][4] = a4; }
    __syncthreads();
    if (tid < 5)
        partials[(long long)blk * 5 + tid] = sm[0][tid] + sm[1][tid] + sm[2][tid] + sm[3][tid];
}

__global__ void head_final_kernel(const float* __restrict__ partials, const float* __restrict__ bout,
                                  float* __restrict__ out)
{
    const int tid = threadIdx.x;
    if (tid >= 40) return;
    const int b = tid / 5, c = tid % 5;
    float s = bout[c];
    const float* p = partials + (long long)b * 64 * 5 + c;
    for (int ck = 0; ck < 64; ++ck) s += p[ck * 5];
    out[tid] = s;   // reference output dtype is float32
}

// ---------------------------------------------------------------------------
extern "C" void kernel_launch(void* const* d_in, const int* in_sizes, int n_in,
                              void* d_out, int out_size, void* d_ws, size_t ws_size,
                              hipStream_t stream)
{
    (void)in_sizes; (void)n_in; (void)out_size; (void)ws_size;
    const int*   x_tok = (const int*)  d_in[0];
    const float* emb   = (const float*)d_in[2];
    const float* Wq    = (const float*)d_in[3];
    const float* bq    = (const float*)d_in[4];
    const float* Wk    = (const float*)d_in[5];
    const float* bk    = (const float*)d_in[6];
    const float* Wv    = (const float*)d_in[7];
    const float* bv    = (const float*)d_in[8];
    const float* Wo    = (const float*)d_in[9];
    const float* bo    = (const float*)d_in[10];
    const float* gma   = (const float*)d_in[11];
    const float* bta   = (const float*)d_in[12];
    const float* W1    = (const float*)d_in[13];
    const float* b1    = (const float*)d_in[14];
    const float* W2    = (const float*)d_in[15];
    const float* b2    = (const float*)d_in[16];
    const float* Wout  = (const float*)d_in[17];
    const float* bout  = (const float*)d_in[18];

    char* ws = (char*)d_ws;
    size_t off = 0;
    auto take = [&](size_t bytes) { char* p = ws + off; off += (bytes + 255) & ~(size_t)255; return p; };
    f16_t* wT    = (f16_t*)take(18874368ULL * 2);  // transposed f16 weights
    f16_t* hb    = (f16_t*)take(2097152ULL * 2);   // residual stream (f16)
    f16_t* qkv   = (f16_t*)take(6291456ULL * 2);   // [4096][1536] (Q,K used)
    f16_t* Vt    = (f16_t*)take(2097152ULL * 2);   // [64][64][512]
    f16_t* ao    = (f16_t*)take(2097152ULL * 2);   // attn out [4096][512]
    f16_t* f1    = (f16_t*)take(8388608ULL * 2);   // ffn hidden [4096][2048]
    f16_t* t16   = (f16_t*)take(4ULL * 2097152ULL * 2); // split-K f16 partials
    float* qkvb  = (float*)take(9216ULL * 4);
    float* parts = (float*)take(2560ULL * 4);

    wconv_kernel <<<dim3(18432), dim3(32, 8), 0, stream>>>(Wq, Wk, Wv, Wo, W1, W2, wT);
    biascat_kernel<<<dim3(36), 256, 0, stream>>>(bq, bk, bv, qkvb);
    embed_kernel <<<dim3(4096), 256, 0, stream>>>(x_tok, emb, hb);

    for (int l = 0; l < 6; ++l) {
        const f16_t* wl = wT + (long long)l * LSTR;
        // QKV: [4096,512]@[512,1536]; V heads written transposed to Vt
        gemm_kernel<64,128,64,2,2,1,0,1><<<dim3(64,12,1),256,0,stream>>>(hb, wl, qkvb + l*1536,
            qkv, Vt, 4096,1536,512, 512,512,1536, 1, 0,0,0,0,0,0);
        // flash attention: softmax(QK^T)V -> ao, S never materialized
        attn_flash_kernel<<<dim3(8,64),256,0,stream>>>(qkv, Vt, ao);
        // O proj: 64x128 split-K x2 (512 blocks) -> t16 slices
        gemm_kernel<64,128,64,2,2,1,0,0><<<dim3(64,4,2),256,0,stream>>>(ao, wl + 786432, nullptr,
            t16, nullptr, 4096,512,256, 512,512,512, 1, 256LL,0LL, 256LL,0LL, 2097152LL,0LL);
        add_ln_kernel<<<dim3(1024),256,0,stream>>>(t16, 2, 2097152LL, bo + l*512,
            gma + l*512, bta + l*512, hb);
        // FFN1 + relu -> f1 f16 (1024 blocks)
        gemm_kernel<64,128,64,2,2,1,1,0><<<dim3(64,16,1),256,0,stream>>>(hb, wl + 1048576, b1 + l*2048,
            f1, nullptr, 4096,2048,512, 512,512,2048, 1, 0,0,0,0,0,0);
        // FFN2: split-K x4 (1024 blocks) -> t16 slices
        gemm_kernel<64,128,64,2,2,1,0,0><<<dim3(64,4,4),256,0,stream>>>(f1, wl + 2097152, nullptr,
            t16, nullptr, 4096,512,512, 2048,2048,512, 1, 512LL,0LL, 512LL,0LL, 2097152LL,0LL);
        add_ln_kernel<<<dim3(1024),256,0,stream>>>(t16, 4, 2097152LL, b2 + l*512,
            gma + l*512, bta + l*512, hb);
    }

    head_partial_kernel<<<dim3(512),256,0,stream>>>(hb, Wout, parts);
    head_final_kernel  <<<dim3(1),64,0,stream>>>(parts, bout, (float*)d_out);
}

// Round 8
// 566.052 us; speedup vs baseline: 2.2091x; 1.0399x over previous
//
#include <hip/hip_runtime.h>
#include <hip/hip_bf16.h>

// ---------------------------------------------------------------------------
// 6-layer transformer forward, MI355X. f16 MFMA compute, f32 stats.
// Round 8: FFN1 and FFN2 slices moved to the m97-proven 128x128/BK=32 tile
//          (512-block grids, 2/CU uniform). QKV/O-proj unchanged (64x128).
// ---------------------------------------------------------------------------

typedef _Float16 f16_t;
typedef _Float16 f16x8 __attribute__((ext_vector_type(8)));
typedef _Float16 f16x4 __attribute__((ext_vector_type(4)));
typedef _Float16 f16x2 __attribute__((ext_vector_type(2)));
typedef float    f32x4 __attribute__((ext_vector_type(4)));

#define LSTR 3145728LL  // per-layer transposed-weight stride (f16 elems)

__device__ __forceinline__ void gl_lds16(const f16_t* g, f16_t* l) {
    __builtin_amdgcn_global_load_lds(
        (const __attribute__((address_space(1))) unsigned int*)g,
        (__attribute__((address_space(3))) unsigned int*)l, 16, 0, 0);
}

// ---------------- pipelined batched GEMM: C = A[M,K] * (Bt[N,K])^T + bias ---
// A, Bt f16 row-major. blockIdx.z -> zh=z/zmod, zl=z%zmod; per-operand strides.
// Split-K via zmod=1: sAhi/sBhi = K-slice offset, sChi = C-slice stride.
// LDS: linear dest (global_load_lds), XOR-swizzled 16B k-chunk on BOTH the
// global source and the LDS read offset (rule #21). BK=64: swz=row&7;
// BK=32: swz=(row>>1)&3.
// VOUT=1 (QKV): cols>=1024 are V heads -> written transposed to vt
// ([b*8+h][64][512]) as f16x4 (4 consecutive t per fragment); qkv gets Q,K.
template<int BM, int BN, int BK, int WR, int WC, int OUTF16, int RELU, int VOUT>
__global__ void __launch_bounds__(256)
gemm_kernel(const f16_t* __restrict__ A, const f16_t* __restrict__ B,
            const float* __restrict__ bias, void* __restrict__ Cout,
            f16_t* __restrict__ vt,
            int M, int N, int K, int lda, int ldb, int ldc, int zmod,
            long long sAhi, long long sAlo, long long sBhi, long long sBlo,
            long long sChi, long long sClo)
{
    constexpr int WMT = BM / WR;
    constexpr int WNT = BN / WC;
    constexpr int MR  = WMT / 16;
    constexpr int NR  = WNT / 16;
    constexpr int KK  = BK / 32;        // 16x16x32 MFMA k-substeps per K-step
    constexpr int CPR = BK / 8;         // 16B chunks per LDS row
    constexpr int RS  = (BK == 32) ? 1 : 0;
    constexpr int IA  = BM * BK / 2048; // global_load_lds issues per thread
    constexpr int IB  = BN * BK / 2048;
    __shared__ __align__(16) f16_t As[2][BM][BK];
    __shared__ __align__(16) f16_t Bs[2][BN][BK];

    const int tid  = threadIdx.x;
    const int wid  = tid >> 6, lane = tid & 63;
    const int wr   = wid / WC, wc = wid % WC;
    const int z    = blockIdx.z;
    const int zh   = z / zmod, zl = z % zmod;
    const f16_t* Ab = A + (long long)zh * sAhi + (long long)zl * sAlo;
    const f16_t* Bb = B + (long long)zh * sBhi + (long long)zl * sBlo;
    const int m0 = blockIdx.x * BM;
    const int n0 = blockIdx.y * BN;

    f32x4 acc[MR][NR] = {};

    // ---- staging addresses: chunk c=i*256+tid; row=c/CPR, j=c%CPR, j^=swz
    const f16_t* srcA[IA]; const f16_t* srcB[IB];
#pragma unroll
    for (int i = 0; i < IA; ++i) {
        const int c = i * 256 + tid, row = c / CPR;
        const int kch = (c % CPR) ^ ((row >> RS) & (CPR - 1));
        srcA[i] = Ab + (long long)(m0 + row) * lda + kch * 8;
    }
#pragma unroll
    for (int i = 0; i < IB; ++i) {
        const int c = i * 256 + tid, row = c / CPR;
        const int kch = (c % CPR) ^ ((row >> RS) & (CPR - 1));
        srcB[i] = Bb + (long long)(n0 + row) * ldb + kch * 8;
    }
    auto stage = [&](int bf_, int t) {
        const int k0 = t * BK;
#pragma unroll
        for (int i = 0; i < IA; ++i)
            gl_lds16(srcA[i] + k0, &As[bf_][0][0] + (i * 256 + wid * 64) * 8);
#pragma unroll
        for (int i = 0; i < IB; ++i)
            gl_lds16(srcB[i] + k0, &Bs[bf_][0][0] + (i * 256 + wid * 64) * 8);
    };

    // ---- fragment read offsets (bytes), swizzled to match staged layout
    const int l15 = lane & 15;
    const int g   = lane >> 4;
    int aoff[MR][KK], boff[NR][KK];
#pragma unroll
    for (int m = 0; m < MR; ++m) {
        const int row = wr * WMT + m * 16 + l15;
        const int swz = ((row >> RS) & (CPR - 1)) << 4;
#pragma unroll
        for (int kk = 0; kk < KK; ++kk)
            aoff[m][kk] = ((row * BK + kk * 32 + g * 8) * 2) ^ swz;
    }
#pragma unroll
    for (int n = 0; n < NR; ++n) {
        const int row = wc * WNT + n * 16 + l15;
        const int swz = ((row >> RS) & (CPR - 1)) << 4;
#pragma unroll
        for (int kk = 0; kk < KK; ++kk)
            boff[n][kk] = ((row * BK + kk * 32 + g * 8) * 2) ^ swz;
    }

    const int NT = K / BK;
    stage(0, 0);
    __syncthreads();                    // drains vmcnt before barrier

    int buf = 0;
    for (int t = 0; t < NT; ++t) {
        if (t + 1 < NT) stage(buf ^ 1, t + 1);   // loads fly during MFMA
        const char* Al = (const char*)&As[buf][0][0];
        const char* Bl = (const char*)&Bs[buf][0][0];
        f16x8 af[MR][KK], bfr[NR][KK];
#pragma unroll
        for (int m = 0; m < MR; ++m)
#pragma unroll
            for (int kk = 0; kk < KK; ++kk) af[m][kk] = *(const f16x8*)(Al + aoff[m][kk]);
#pragma unroll
        for (int n = 0; n < NR; ++n)
#pragma unroll
            for (int kk = 0; kk < KK; ++kk) bfr[n][kk] = *(const f16x8*)(Bl + boff[n][kk]);
#pragma unroll
        for (int kk = 0; kk < KK; ++kk)
#pragma unroll
            for (int m = 0; m < MR; ++m)
#pragma unroll
                for (int n = 0; n < NR; ++n)
                    acc[m][n] = __builtin_amdgcn_mfma_f32_16x16x32_f16(af[m][kk], bfr[n][kk], acc[m][n], 0, 0, 0);
        __syncthreads();                // drains vmcnt+lgkmcnt, swap safe
        buf ^= 1;
    }

    const long long cOff = (long long)zh * sChi + (long long)zl * sClo;
    const int rbase = (lane >> 4) * 4;  // C/D: row=(lane>>4)*4+r, col=lane&15
#pragma unroll
    for (int m = 0; m < MR; ++m) {
        const int row = m0 + wr * WMT + m * 16 + rbase;
#pragma unroll
        for (int n = 0; n < NR; ++n) {
            const int col = n0 + wc * WNT + n * 16 + l15;
            const float bb = bias ? bias[col] : 0.0f;
            if (VOUT && col >= 1024) {  // V head -> transposed f16x4 store
                const int hh = (col - 1024) >> 6, dv = (col - 1024) & 63;
                const int bb_ = row >> 9, t0 = row & 511;
                f16x4 v4;
#pragma unroll
                for (int r = 0; r < 4; ++r) v4[r] = (f16_t)(acc[m][n][r] + bb);
                *(f16x4*)&vt[((long long)((bb_ * 8 + hh) * 64 + dv)) * 512 + t0] = v4;
            } else {
#pragma unroll
                for (int r = 0; r < 4; ++r) {
                    float v = acc[m][n][r] + bb;
                    if (RELU) v = fmaxf(v, 0.0f);
                    const long long idx = cOff + (long long)(row + r) * ldc + col;
                    if (OUTF16) ((f16_t*)Cout)[idx] = (f16_t)v;
                    else        ((float*)Cout)[idx] = v;
                }
            }
        }
    }
}

// ------- flash attention per (b,h, 64-q tile): softmax(Q K^T) V -> ao -------
__global__ void __launch_bounds__(256)
attn_flash_kernel(const f16_t* __restrict__ qkv, const f16_t* __restrict__ Vt,
                  f16_t* __restrict__ ao)
{
    __shared__ __align__(16) f16_t Ks[512 * 64];   // 64KB
    __shared__ __align__(16) f16_t Qs[64 * 64];    //  8KB
    __shared__ __align__(16) f16_t Ps[4][16 * 64]; //  8KB (per-wave private)
    const int tid = threadIdx.x, wid = tid >> 6, lane = tid & 63;
    const int l15 = lane & 15, g = lane >> 4;
    const int z = blockIdx.y, b = z >> 3, hh = z & 7;
    const int q0 = blockIdx.x * 64;
    const f16_t* Kbase = qkv + (long long)b * 512 * 1536 + 512 + hh * 64;
    const f16_t* Qbase = qkv + (long long)(b * 512 + q0) * 1536 + hh * 64;
    const f16_t* Vbase = Vt + (long long)z * 32768;

    // stage K[512][64] and Q[64][64]; linear LDS dest, inverse-swizzled source
#pragma unroll
    for (int i = 0; i < 16; ++i) {
        const int c = i * 256 + tid, t = c >> 3, j = c & 7;
        gl_lds16(Kbase + (long long)t * 1536 + ((j ^ (t & 7)) << 3), Ks + c * 8);
    }
#pragma unroll
    for (int i = 0; i < 2; ++i) {
        const int c = i * 256 + tid, t = c >> 3, j = c & 7;
        gl_lds16(Qbase + (long long)t * 1536 + ((j ^ (t & 7)) << 3), Qs + c * 8);
    }
    __syncthreads();

    // hoisted Q B-frags: this wave's q rows = wid*16 + l15
    const int q = wid * 16 + l15;
    f16x8 qf[2];
#pragma unroll
    for (int k = 0; k < 2; ++k)
        qf[k] = *(const f16x8*)(Qs + q * 64 + (((k * 4 + g) ^ (l15 & 7)) << 3));

    f32x4 ov[4] = {};                   // O rows q=g*4+r, cols dv=n*16+l15
    float m_run = -1e30f, l_run = 0.0f;
    f16_t* Pw = &Ps[wid][0];

    for (int ck = 0; ck < 8; ++ck) {
        const int kc0 = ck * 64;
        f16x8 vf[4][2];
#pragma unroll
        for (int n = 0; n < 4; ++n)
#pragma unroll
            for (int k = 0; k < 2; ++k)
                vf[n][k] = *(const f16x8*)(Vbase + (n * 16 + l15) * 512 + kc0 + k * 32 + g * 8);
        // S^T = K_chunk . Q^T : rows=keys, cols=q
        f32x4 s[4] = {};
#pragma unroll
        for (int k = 0; k < 2; ++k)
#pragma unroll
            for (int m = 0; m < 4; ++m) {
                const int key = kc0 + m * 16 + l15;
                const f16x8 a = *(const f16x8*)(Ks + key * 64 + (((k * 4 + g) ^ (key & 7)) << 3));
                s[m] = __builtin_amdgcn_mfma_f32_16x16x32_f16(a, qf[k], s[m], 0, 0, 0);
            }
        // online softmax over keys for q = l15
        float cmax = -1e30f;
#pragma unroll
        for (int m = 0; m < 4; ++m)
#pragma unroll
            for (int r = 0; r < 4; ++r) cmax = fmaxf(cmax, s[m][r]);
        cmax = fmaxf(cmax, __shfl_xor(cmax, 16, 64));
        cmax = fmaxf(cmax, __shfl_xor(cmax, 32, 64));
        const float mnew = fmaxf(m_run, cmax);
        const float corr = __expf(m_run - mnew);
        float csum = 0.0f;
#pragma unroll
        for (int m = 0; m < 4; ++m) {
            f16x4 p4;
#pragma unroll
            for (int r = 0; r < 4; ++r) {
                const float pe = __expf(s[m][r] - mnew);
                csum += pe;
                p4[r] = (f16_t)pe;
            }
            *(f16x4*)(Pw + l15 * 64 + ((((m * 2 + (g >> 1)) ^ (l15 & 7))) << 3) + ((g & 1) << 2)) = p4;
        }
        csum += __shfl_xor(csum, 16, 64);
        csum += __shfl_xor(csum, 32, 64);
        l_run = l_run * corr + csum;
        m_run = mnew;
        float cr[4];
#pragma unroll
        for (int r = 0; r < 4; ++r) cr[r] = __shfl(corr, g * 4 + r, 64);
#pragma unroll
        for (int n = 0; n < 4; ++n)
#pragma unroll
            for (int r = 0; r < 4; ++r) ov[n][r] *= cr[r];
#pragma unroll
        for (int k = 0; k < 2; ++k) {
            const f16x8 pf = *(const f16x8*)(Pw + l15 * 64 + (((k * 4 + g) ^ (l15 & 7)) << 3));
#pragma unroll
            for (int n = 0; n < 4; ++n)
                ov[n] = __builtin_amdgcn_mfma_f32_16x16x32_f16(pf, vf[n][k], ov[n], 0, 0, 0);
        }
    }

    const float inv = 1.0f / l_run;
    float ir[4];
#pragma unroll
    for (int r = 0; r < 4; ++r) ir[r] = __shfl(inv, g * 4 + r, 64);
#pragma unroll
    for (int n = 0; n < 4; ++n)
#pragma unroll
        for (int r = 0; r < 4; ++r) {
            const long long row = b * 512 + q0 + wid * 16 + g * 4 + r;
            ao[row * 512 + hh * 64 + n * 16 + l15] = (f16_t)(ov[n][r] * ir[r]);
        }
}

// ---------------- weight convert+transpose f32 -> f16, [K,N] -> [N,K] -------
__global__ void wconv_kernel(const float* __restrict__ Wq, const float* __restrict__ Wk,
                             const float* __restrict__ Wv, const float* __restrict__ Wo,
                             const float* __restrict__ W1, const float* __restrict__ W2,
                             f16_t* __restrict__ wT)
{
    __shared__ float tile[32][33];
    const int t     = blockIdx.x;       // 18432 tiles = 6 layers * 3072
    const int layer = t / 3072;
    const int r     = t % 3072;
    const float* src; f16_t* dst; int R, C, tt;
    if (r < 1024) {                     // Wq,Wk,Wv,Wo: [512,512]
        const int mat = r >> 8; tt = r & 255; R = 512; C = 512;
        const float* s4 = (mat == 0) ? Wq : (mat == 1) ? Wk : (mat == 2) ? Wv : Wo;
        src = s4 + (long long)layer * 262144;
        dst = wT + (long long)layer * LSTR + (long long)mat * 262144;
    } else if (r < 2048) {              // W1: [512,2048] -> [2048,512]
        tt = r - 1024; R = 512; C = 2048;
        src = W1 + (long long)layer * 1048576;
        dst = wT + (long long)layer * LSTR + 1048576;
    } else {                            // W2: [2048,512] -> [512,2048]
        tt = r - 2048; R = 2048; C = 512;
        src = W2 + (long long)layer * 1048576;
        dst = wT + (long long)layer * LSTR + 2097152;
    }
    const int tC = C >> 5;
    const int tr = tt / tC, tc = tt % tC;
    const int r0 = tr * 32, c0 = tc * 32;
    const int tx = threadIdx.x, ty = threadIdx.y;
#pragma unroll
    for (int i = 0; i < 4; ++i)
        tile[ty + 8 * i][tx] = src[(long long)(r0 + ty + 8 * i) * C + c0 + tx];
    __syncthreads();
#pragma unroll
    for (int i = 0; i < 4; ++i)
        dst[(long long)(c0 + ty + 8 * i) * R + r0 + tx] = (f16_t)tile[tx][ty + 8 * i];
}

// ---------------- concat per-layer [bq|bk|bv] -> [6][1536] ------------------
__global__ void biascat_kernel(const float* __restrict__ bq, const float* __restrict__ bk,
                               const float* __restrict__ bv, float* __restrict__ qkvb)
{
    const int i = blockIdx.x * 256 + threadIdx.x;
    if (i >= 9216) return;
    const int l = i / 1536, c = i % 1536;
    float v;
    if (c < 512)       v = bq[l * 512 + c];
    else if (c < 1024) v = bk[l * 512 + c - 512];
    else               v = bv[l * 512 + c - 1024];
    qkvb[i] = v;
}

// ---------------- embedding gather + sinusoidal PE (f16 stream) -------------
__global__ void embed_kernel(const int* __restrict__ xt, const float* __restrict__ emb,
                             f16_t* __restrict__ hb)
{
    const int row = blockIdx.x;         // b*512 + t
    const int t   = row & 511;
    const int tok = xt[row];
    const int tid = threadIdx.x;
#pragma unroll
    for (int s = 0; s < 2; ++s) {
        const int d = tid + s * 256;
        const int i = d >> 1;
        const float inv = expf((float)(2 * i) * (-9.210340371976184f / 512.0f));
        const float ang = (float)t * inv;
        const float pe  = (d & 1) ? cosf(ang) : sinf(ang);
        hb[(long long)row * 512 + d] = (f16_t)(emb[(long long)tok * 512 + d] + pe);
    }
}

// ---- hb = LN( sum_{s<ns} X[s] + bias + hb ); wave-per-row, no barriers -----
__global__ void __launch_bounds__(256)
add_ln_kernel(const f16_t* __restrict__ X, int ns, long long sstr,
              const float* __restrict__ bias,
              const float* __restrict__ g, const float* __restrict__ b,
              f16_t* __restrict__ Hf)
{
    const int wid = threadIdx.x >> 6, lane = threadIdx.x & 63;
    const long long row = (long long)blockIdx.x * 4 + wid;
    f16_t* h = Hf + row * 512;
    const int c0 = lane * 8;
    const f16x8 hv = *(const f16x8*)&h[c0];
    float v[8];
#pragma unroll
    for (int e = 0; e < 8; ++e) v[e] = (float)hv[e] + bias[c0 + e];
    for (int s = 0; s < ns; ++s) {
        const f16x8 xv = *(const f16x8*)&X[s * sstr + row * 512 + c0];
#pragma unroll
        for (int e = 0; e < 8; ++e) v[e] += (float)xv[e];
    }
    float sum = 0.0f, sq = 0.0f;
#pragma unroll
    for (int e = 0; e < 8; ++e) { sum += v[e]; sq += v[e] * v[e]; }
#pragma unroll
    for (int o = 1; o < 64; o <<= 1) {
        sum += __shfl_xor(sum, o, 64);
        sq  += __shfl_xor(sq,  o, 64);
    }
    const float mu = sum * (1.0f / 512.0f);
    float var = sq * (1.0f / 512.0f) - mu * mu;
    var = fmaxf(var, 0.0f);
    const float rs = rsqrtf(var + 1e-5f);
    f16x8 o8;
#pragma unroll
    for (int e = 0; e < 8; ++e)
        o8[e] = (f16_t)(g[c0 + e] * (v[e] - mu) * rs + b[c0 + e]);
    *(f16x8*)&h[c0] = o8;
}

// ---------------- classifier head: split reduction (hb f16) -----------------
__global__ void head_partial_kernel(const f16_t* __restrict__ hb, const float* __restrict__ Wout,
                                    float* __restrict__ partials)
{
    const int blk = blockIdx.x;         // 8 b * 64 chunks
    const int b = blk >> 6, chunk = blk & 63;
    const int tid = threadIdx.x;
    const f16_t* hp = hb + (long long)b * 262144 + (long long)chunk * 4096;
    float a0 = 0, a1 = 0, a2 = 0, a3 = 0, a4 = 0;
    for (int it = 0; it < 16; ++it) {
        const int idx = it * 256 + tid;
        const float hv = (float)hp[idx];
        const float* w = Wout + ((long long)chunk * 4096 + idx) * 5;
        a0 += hv * w[0]; a1 += hv * w[1]; a2 += hv * w[2]; a3 += hv * w[3]; a4 += hv * w[4];
    }
#pragma unroll
    for (int o = 32; o > 0; o >>= 1) {
        a0 += __shfl_down(a0, o, 64); a1 += __shfl_down(a1, o, 64); a2 += __shfl_down(a2, o, 64);
        a3 += __shfl_down(a3, o, 64); a4 += __shfl_down(a4, o, 64);
    }
    __shared__ float sm[4][5];
    const int lane = tid & 63, w = tid >> 6;
    if (lane == 0) { sm[w][0] = a0; sm[w][1] = a1; sm[w][2] = a2; sm[w][3] = a3; sm[w][4] = a4; }
    __syncthreads();
    if (tid < 5)
        partials[(long long)blk * 5 + tid] = sm[0][tid] + sm[1][tid] + sm[2][tid] + sm[3][tid];
}

__global__ void head_final_kernel(const float* __restrict__ partials, const float* __restrict__ bout,
                                  float* __restrict__ out)
{
    const int tid = threadIdx.x;
    if (tid >= 40) return;
    const int b = tid / 5, c = tid % 5;
    float s = bout[c];
    const float* p = partials + (long long)b * 64 * 5 + c;
    for (int ck = 0; ck < 64; ++ck) s += p[ck * 5];
    out[tid] = s;   // reference output dtype is float32
}

// ---------------------------------------------------------------------------
extern "C" void kernel_launch(void* const* d_in, const int* in_sizes, int n_in,
                              void* d_out, int out_size, void* d_ws, size_t ws_size,
                              hipStream_t stream)
{
    (void)in_sizes; (void)n_in; (void)out_size; (void)ws_size;
    const int*   x_tok = (const int*)  d_in[0];
    const float* emb   = (const float*)d_in[2];
    const float* Wq    = (const float*)d_in[3];
    const float* bq    = (const float*)d_in[4];
    const float* Wk    = (const float*)d_in[5];
    const float* bk    = (const float*)d_in[6];
    const float* Wv    = (const float*)d_in[7];
    const float* bv    = (const float*)d_in[8];
    const float* Wo    = (const float*)d_in[9];
    const float* bo    = (const float*)d_in[10];
    const float* gma   = (const float*)d_in[11];
    const float* bta   = (const float*)d_in[12];
    const float* W1    = (const float*)d_in[13];
    const float* b1    = (const float*)d_in[14];
    const float* W2    = (const float*)d_in[15];
    const float* b2    = (const float*)d_in[16];
    const float* Wout  = (const float*)d_in[17];
    const float* bout  = (const float*)d_in[18];

    char* ws = (char*)d_ws;
    size_t off = 0;
    auto take = [&](size_t bytes) { char* p = ws + off; off += (bytes + 255) & ~(size_t)255; return p; };
    f16_t* wT    = (f16_t*)take(18874368ULL * 2);  // transposed f16 weights
    f16_t* hb    = (f16_t*)take(2097152ULL * 2);   // residual stream (f16)
    f16_t* qkv   = (f16_t*)take(6291456ULL * 2);   // [4096][1536] (Q,K used)
    f16_t* Vt    = (f16_t*)take(2097152ULL * 2);   // [64][64][512]
    f16_t* ao    = (f16_t*)take(2097152ULL * 2);   // attn out [4096][512]
    f16_t* f1    = (f16_t*)take(8388608ULL * 2);   // ffn hidden [4096][2048]
    f16_t* t16   = (f16_t*)take(4ULL * 2097152ULL * 2); // split-K f16 partials
    float* qkvb  = (float*)take(9216ULL * 4);
    float* parts = (float*)take(2560ULL * 4);

    wconv_kernel <<<dim3(18432), dim3(32, 8), 0, stream>>>(Wq, Wk, Wv, Wo, W1, W2, wT);
    biascat_kernel<<<dim3(36), 256, 0, stream>>>(bq, bk, bv, qkvb);
    embed_kernel <<<dim3(4096), 256, 0, stream>>>(x_tok, emb, hb);

    for (int l = 0; l < 6; ++l) {
        const f16_t* wl = wT + (long long)l * LSTR;
        // QKV: [4096,512]@[512,1536]; V heads written transposed to Vt
        gemm_kernel<64,128,64,2,2,1,0,1><<<dim3(64,12,1),256,0,stream>>>(hb, wl, qkvb + l*1536,
            qkv, Vt, 4096,1536,512, 512,512,1536, 1, 0,0,0,0,0,0);
        // flash attention: softmax(QK^T)V -> ao, S never materialized
        attn_flash_kernel<<<dim3(8,64),256,0,stream>>>(qkv, Vt, ao);
        // O proj: 64x128 split-K x2 (512 blocks) -> t16 slices
        gemm_kernel<64,128,64,2,2,1,0,0><<<dim3(64,4,2),256,0,stream>>>(ao, wl + 786432, nullptr,
            t16, nullptr, 4096,512,256, 512,512,512, 1, 256LL,0LL, 256LL,0LL, 2097152LL,0LL);
        add_ln_kernel<<<dim3(1024),256,0,stream>>>(t16, 2, 2097152LL, bo + l*512,
            gma + l*512, bta + l*512, hb);
        // FFN1 + relu -> f1 f16: 128x128/BK=32 (512 blocks, 2/CU uniform)
        gemm_kernel<128,128,32,2,2,1,1,0><<<dim3(32,16,1),256,0,stream>>>(hb, wl + 1048576, b1 + l*2048,
            f1, nullptr, 4096,2048,512, 512,512,2048, 1, 0,0,0,0,0,0);
        // FFN2: 128x128/BK=32 split-K x4 (512 blocks, 2/CU) -> t16 slices
        gemm_kernel<128,128,32,2,2,1,0,0><<<dim3(32,4,4),256,0,stream>>>(f1, wl + 2097152, nullptr,
            t16, nullptr, 4096,512,512, 2048,2048,512, 1, 512LL,0LL, 512LL,0LL, 2097152LL,0LL);
        add_ln_kernel<<<dim3(1024),256,0,stream>>>(t16, 4, 2097152LL, b2 + l*512,
            gma + l*512, bta + l*512, hb);
    }

    head_partial_kernel<<<dim3(512),256,0,stream>>>(hb, Wout, parts);
    head_final_kernel  <<<dim3(1),64,0,stream>>>(parts, bout, (float*)d_out);
}